// Round 1
// baseline (3211.339 us; speedup 1.0000x reference)
//
#include <hip/hip_runtime.h>
#include <math.h>

// ---------------- problem constants ----------------
constexpr int M1 = 2000, M2 = 400, BS = 8;
constexpr int AT = M1 + M2;            // 2400
constexpr int NN = BS * AT;            // 19200 nodes
constexpr int E1 = 60000, E2 = 20000, E3 = 20000;
constexpr int ET = E1 + E2 + E3;       // 100000
constexpr int H = 64, F = 64, NG = 50, L = 4, C = 4;
constexpr float CUTOFF = 10.0f;
constexpr float LOG2F_ = 0.6931471805599453f;

// smearing: offset[k] = 10k/49, coeff = -0.5/(10/49)^2 = -12.005
constexpr float SMEAR_STEP = 10.0f / 49.0f;
constexpr float SMEAR_COEFF = -12.005f;
constexpr float PI_OVER_CUT = 0.31415926535897932f; // pi/10

// ---------------- workspace layout (bytes) ----------------
constexpr size_t O_H     = 0;                         // h      [NN,64] f32
constexpr size_t O_DELTA = O_H     + (size_t)NN * 64 * 4;
constexpr size_t O_XG    = O_DELTA + (size_t)NN * 64 * 4;   // xg [3,NN,64]
constexpr size_t O_AGG   = O_XG    + (size_t)3 * NN * 64 * 4; // agg3 [3,NN,64]
constexpr size_t O_W     = O_AGG   + (size_t)3 * NN * 64 * 4; // W  [ET,64]
constexpr size_t O_INT   = O_W     + (size_t)ET * 64 * 4;
// int region (element offsets from O_INT):
constexpr int I_DEG   = 0;          // [3*AT]   (zeroed)
constexpr int I_CUR   = 7200;       // [3*AT]   (zeroed)
constexpr int I_CDEG  = 14400;      // [16]     (zeroed, 12 used)
constexpr int I_CCUR  = 14416;      // [16]     (zeroed, 12 used)
constexpr int I_ZEND  = 14432;      // end of zeroed region
constexpr int I_BASE  = 14432;      // [3*(AT+1)] pad to 7204
constexpr int I_CBASE = 21636;      // [16] (15 used)
constexpr int I_CSR   = 21652;      // [ET]
constexpr int I_CCSR  = 121652;     // [ET]

__device__ inline float sspf(float x) {
    // shifted softplus: log(1+exp(x)) - log(2), numerically stable
    return fmaxf(x, 0.0f) + log1pf(expf(-fabsf(x))) - LOG2F_;
}

__device__ inline int graph_off(int g) { return g == 0 ? 0 : (g == 1 ? E1 : E1 + E2); }

// ---------------- setup kernels ----------------
__global__ void k_init_h(const int* __restrict__ sites, const int* __restrict__ sites_p,
                         const float* __restrict__ emb_w, const float* __restrict__ emb_p_w,
                         float* __restrict__ h) {
    int idx = blockIdx.x * blockDim.x + threadIdx.x;
    if (idx >= NN * 64) return;
    int f = idx & 63;
    int n = idx >> 6;
    int b = n / AT;
    int i = n - b * AT;
    float v;
    if (i < M1) v = emb_w[sites[b * M1 + i] * H + f];
    else        v = emb_p_w[sites_p[b * M2 + (i - M1)] * H + f];
    h[idx] = v;
}

__global__ void k_deg(const int* __restrict__ ei1, const int* __restrict__ ei2,
                      const int* __restrict__ ei3, const int* __restrict__ c1,
                      const int* __restrict__ c2, const int* __restrict__ c3,
                      int* __restrict__ deg, int* __restrict__ cdeg) {
    int idx = blockIdx.x * blockDim.x + threadIdx.x;
    if (idx >= ET) return;
    int g, e; const int* ei; const int* cl;
    if (idx < E1)            { g = 0; e = idx;          ei = ei1; cl = c1; }
    else if (idx < E1 + E2)  { g = 1; e = idx - E1;     ei = ei2; cl = c2; }
    else                     { g = 2; e = idx - E1 - E2; ei = ei3; cl = c3; }
    atomicAdd(&deg[g * AT + ei[2 * e + 1]], 1);
    atomicAdd(&cdeg[g * 4 + cl[e]], 1);
}

// one block per graph: exclusive scan of deg[g][0..AT) -> base[g][0..AT]
__global__ void k_scan(const int* __restrict__ deg, int* __restrict__ base,
                       const int* __restrict__ cdeg, int* __restrict__ cbase) {
    const int T = 256, CH = 10; // 2560 >= 2400
    __shared__ int lsum[T];
    int g = blockIdx.x;
    int t = threadIdx.x;
    int loc[CH];
    int s = 0;
    #pragma unroll
    for (int i = 0; i < CH; i++) {
        int idx = t * CH + i;
        int v = (idx < AT) ? deg[g * AT + idx] : 0;
        loc[i] = s;
        s += v;
    }
    lsum[t] = s;
    __syncthreads();
    for (int off = 1; off < T; off <<= 1) {
        int v = 0;
        if (t >= off) v = lsum[t - off];
        __syncthreads();
        lsum[t] += v;
        __syncthreads();
    }
    int tb = lsum[t] - s; // exclusive prefix for this thread
    #pragma unroll
    for (int i = 0; i < CH; i++) {
        int idx = t * CH + i;
        if (idx < AT) base[g * (AT + 1) + idx] = tb + loc[i];
    }
    if (t == T - 1) base[g * (AT + 1) + AT] = lsum[T - 1];
    // color bases (global positions in ccsr), done serially by one thread
    if (g == 0 && t == 0) {
        for (int gg = 0; gg < 3; gg++) {
            int run = graph_off(gg);
            for (int c = 0; c < C; c++) { cbase[gg * 5 + c] = run; run += cdeg[gg * 4 + c]; }
            cbase[gg * 5 + C] = run;
        }
    }
}

__global__ void k_fill(const int* __restrict__ ei1, const int* __restrict__ ei2,
                       const int* __restrict__ ei3, const int* __restrict__ c1,
                       const int* __restrict__ c2, const int* __restrict__ c3,
                       const int* __restrict__ base, int* __restrict__ cur,
                       int* __restrict__ csr, const int* __restrict__ cbase,
                       int* __restrict__ ccur, int* __restrict__ ccsr) {
    int idx = blockIdx.x * blockDim.x + threadIdx.x;
    if (idx >= ET) return;
    int g, e; const int* ei; const int* cl;
    if (idx < E1)            { g = 0; e = idx;          ei = ei1; cl = c1; }
    else if (idx < E1 + E2)  { g = 1; e = idx - E1;     ei = ei2; cl = c2; }
    else                     { g = 2; e = idx - E1 - E2; ei = ei3; cl = c3; }
    int dst = ei[2 * e + 1];
    int p = base[g * (AT + 1) + dst] + atomicAdd(&cur[g * AT + dst], 1);
    csr[graph_off(g) + p] = e;
    int c = cl[e];
    int q = cbase[g * 5 + c] + atomicAdd(&ccur[g * 4 + c], 1);
    ccsr[q] = e;
}

// ---------------- per-layer kernels ----------------
// Edge MLP: W[e][f] = (ssp(attr@w1[c]+b1[c]) @ w2[c] + b2[c]) * Ccut
// One wave per edge-chunk, edges pre-sorted by (g,color); weight columns in VGPRs.
constexpr int EW_CH = 32;                       // edges per wave
constexpr int B1G = (E1 + 4 * EW_CH - 1) / (4 * EW_CH); // 469
constexpr int B2G = (E2 + 4 * EW_CH - 1) / (4 * EW_CH); // 157
constexpr int B3G = (E3 + 4 * EW_CH - 1) / (4 * EW_CH); // 157
constexpr int BPC = B1G + B2G + B3G;            // 783 blocks per color

__global__ __launch_bounds__(256) void k_edge_mlp(
    const int* __restrict__ ccsr, const int* __restrict__ cbase,
    const float* __restrict__ ew1, const float* __restrict__ ew2,
    const float* __restrict__ ew3,
    const float* __restrict__ mlp_w1, const float* __restrict__ mlp_b1,
    const float* __restrict__ mlp_w2, const float* __restrict__ mlp_b2,
    float* __restrict__ Wout, int l) {
    const int lane = threadIdx.x & 63;
    const int wv = threadIdx.x >> 6;
    int bid = blockIdx.x;
    int c = bid / BPC;
    int r = bid - c * BPC;
    int g, blk;
    if (r < B1G)            { g = 0; blk = r; }
    else if (r < B1G + B2G) { g = 1; blk = r - B1G; }
    else                    { g = 2; blk = r - B1G - B2G; }
    int rbase = cbase[g * 5 + c], rend = cbase[g * 5 + c + 1];
    int s = rbase + (blk * 4 + wv) * EW_CH;
    if (s >= rend) return;
    int e_hi = min(s + EW_CH, rend);
    const float* ew = (g == 0) ? ew1 : (g == 1 ? ew2 : ew3);
    int goff = graph_off(g);
    size_t wb = (size_t)((l * 3 + g) * C + c);
    const float* w1 = mlp_w1 + wb * NG * F;
    const float* w2 = mlp_w2 + wb * F * F;
    float w1c[NG], w2c[F];
    #pragma unroll
    for (int k = 0; k < NG; k++) w1c[k] = w1[k * F + lane];
    #pragma unroll
    for (int k = 0; k < F; k++) w2c[k] = w2[k * F + lane];
    float b1c = mlp_b1[wb * F + lane];
    float b2c = mlp_b2[wb * F + lane];
    float off = (float)lane * SMEAR_STEP;
    for (int i = s; i < e_hi; i++) {
        int eid = ccsr[i];
        float d = ew[eid];
        float dd = d - off;
        float av = (lane < NG) ? expf(SMEAR_COEFF * dd * dd) : 0.0f;
        float acc = b1c;
        #pragma unroll
        for (int k = 0; k < NG; k++) acc = fmaf(__shfl(av, k), w1c[k], acc);
        float t = sspf(acc);
        float acc2 = b2c;
        #pragma unroll
        for (int j = 0; j < F; j++) acc2 = fmaf(__shfl(t, j), w2c[j], acc2);
        float ccut = 0.5f * (cosf(d * PI_OVER_CUT) + 1.0f);
        Wout[(size_t)(goff + eid) * F + lane] = acc2 * ccut;
    }
}

// x_g = h @ conv_w1[l,g]  (no bias), for all 3 graphs
constexpr int X_ROWS = 16;
constexpr int X_WPG = NN / X_ROWS;  // 1200 waves per graph
__global__ __launch_bounds__(256) void k_lin1(
    const float* __restrict__ h, const float* __restrict__ conv_w1,
    float* __restrict__ xg, int l) {
    const int lane = threadIdx.x & 63;
    int w = blockIdx.x * 4 + (threadIdx.x >> 6);
    int g = w / X_WPG;
    int rw = w - g * X_WPG;
    const float* wm = conv_w1 + (size_t)(l * 3 + g) * H * F;
    float wc[H];
    #pragma unroll
    for (int k = 0; k < H; k++) wc[k] = wm[k * F + lane];
    float* xo = xg + (size_t)g * NN * F;
    int r0 = rw * X_ROWS;
    for (int r = r0; r < r0 + X_ROWS; r++) {
        float hv = h[(size_t)r * H + lane];
        float acc = 0.0f;
        #pragma unroll
        for (int k = 0; k < H; k++) acc = fmaf(__shfl(hv, k), wc[k], acc);
        xo[(size_t)r * F + lane] = acc;
    }
}

// Aggregation: one wave per (g,dst), all 8 batches accumulated in registers.
__global__ __launch_bounds__(256) void k_agg(
    const int* __restrict__ csr, const int* __restrict__ base,
    const int* __restrict__ ei1, const int* __restrict__ ei2,
    const int* __restrict__ ei3,
    const float* __restrict__ xg, const float* __restrict__ Wm,
    float* __restrict__ agg3) {
    const int lane = threadIdx.x & 63;
    int w = blockIdx.x * 4 + (threadIdx.x >> 6); // 0..7199
    int g = w / AT;
    int dst = w - g * AT;
    const int* ei = (g == 0) ? ei1 : (g == 1 ? ei2 : ei3);
    int goff = graph_off(g);
    int s = base[g * (AT + 1) + dst];
    int e = base[g * (AT + 1) + dst + 1];
    float acc[BS];
    #pragma unroll
    for (int b = 0; b < BS; b++) acc[b] = 0.0f;
    for (int i = s; i < e; i++) {
        int eid = csr[goff + i];
        int src = ei[2 * eid];
        float wv = Wm[(size_t)(goff + eid) * F + lane];
        const float* xb = xg + ((size_t)g * NN + src) * F + lane;
        #pragma unroll
        for (int b = 0; b < BS; b++)
            acc[b] = fmaf(xb[(size_t)b * AT * F], wv, acc[b]);
    }
    float* ao = agg3 + ((size_t)g * NN + dst) * F + lane;
    #pragma unroll
    for (int b = 0; b < BS; b++) ao[(size_t)b * AT * F] = acc[b];
}

// lin2 + ssp + block-linear, accumulate delta; g==2 folds h += delta
constexpr int N2_ROWS = 8;
__global__ __launch_bounds__(256) void k_node2(
    const float* __restrict__ agg3, const float* __restrict__ conv_w2,
    const float* __restrict__ conv_b2, const float* __restrict__ blk_w,
    const float* __restrict__ blk_b, float* __restrict__ delta,
    float* __restrict__ h, int l, int g) {
    const int lane = threadIdx.x & 63;
    int w = blockIdx.x * 4 + (threadIdx.x >> 6);
    size_t pb = (size_t)(l * 3 + g);
    const float* cw2 = conv_w2 + pb * F * H;
    const float* bw = blk_w + pb * H * H;
    float c2c[F], bwc[H];
    #pragma unroll
    for (int k = 0; k < F; k++) c2c[k] = cw2[k * H + lane];
    #pragma unroll
    for (int k = 0; k < H; k++) bwc[k] = bw[k * H + lane];
    float cb2c = conv_b2[pb * H + lane];
    float bbc = blk_b[pb * H + lane];
    const float* ag = agg3 + (size_t)g * NN * F;
    int r0 = w * N2_ROWS;
    for (int r = r0; r < r0 + N2_ROWS; r++) {
        float av = ag[(size_t)r * F + lane];
        float acc = cb2c;
        #pragma unroll
        for (int k = 0; k < F; k++) acc = fmaf(__shfl(av, k), c2c[k], acc);
        float t = sspf(acc);
        float o = bbc;
        #pragma unroll
        for (int j = 0; j < H; j++) o = fmaf(__shfl(t, j), bwc[j], o);
        size_t ix = (size_t)r * H + lane;
        if (g == 0)      delta[ix] = o;
        else if (g == 1) delta[ix] += o;
        else             h[ix] += delta[ix] + o;
    }
}

// Readout: o[b] = sum_pore h . weff + M2*(b1.W2 + b2), weff = W1@W2
__global__ void k_read(const float* __restrict__ h,
                       const float* __restrict__ w1, const float* __restrict__ b1,
                       const float* __restrict__ w2, const float* __restrict__ b2,
                       float* __restrict__ out) {
    int b = blockIdx.x;
    int lane = threadIdx.x & 63;
    int wv = threadIdx.x >> 6;
    __shared__ float part[4];
    float weff = 0.0f;
    #pragma unroll
    for (int j = 0; j < H / 2; j++) weff = fmaf(w1[lane * (H / 2) + j], w2[j], weff);
    float acc = 0.0f;
    for (int i = wv * (M2 / 4); i < (wv + 1) * (M2 / 4); i++)
        acc += h[((size_t)b * AT + M1 + i) * H + lane];
    float v = acc * weff;
    for (int off = 32; off; off >>= 1) v += __shfl_xor(v, off);
    if (lane == 0) part[wv] = v;
    __syncthreads();
    if (threadIdx.x == 0) {
        float bias = b2[0];
        for (int j = 0; j < H / 2; j++) bias = fmaf(b1[j], w2[j], bias);
        out[b] = part[0] + part[1] + part[2] + part[3] + (float)M2 * bias;
    }
}

// ---------------- launcher ----------------
extern "C" void kernel_launch(void* const* d_in, const int* in_sizes, int n_in,
                              void* d_out, int out_size, void* d_ws, size_t ws_size,
                              hipStream_t stream) {
    const int* sites   = (const int*)d_in[0];
    const int* sites_p = (const int*)d_in[1];
    const int* ei1 = (const int*)d_in[2];
    const float* ew1 = (const float*)d_in[3];
    const int* c1 = (const int*)d_in[4];
    const int* ei2 = (const int*)d_in[5];
    const float* ew2 = (const float*)d_in[6];
    const int* c2 = (const int*)d_in[7];
    const int* ei3 = (const int*)d_in[8];
    const float* ew3 = (const float*)d_in[9];
    const int* c3 = (const int*)d_in[10];
    const float* emb_w   = (const float*)d_in[11];
    const float* emb_p_w = (const float*)d_in[12];
    const float* mlp_w1 = (const float*)d_in[13];
    const float* mlp_b1 = (const float*)d_in[14];
    const float* mlp_w2 = (const float*)d_in[15];
    const float* mlp_b2 = (const float*)d_in[16];
    const float* conv_w1 = (const float*)d_in[17];
    const float* conv_w2 = (const float*)d_in[18];
    const float* conv_b2 = (const float*)d_in[19];
    const float* blk_w = (const float*)d_in[20];
    const float* blk_b = (const float*)d_in[21];
    const float* out_w1 = (const float*)d_in[22];
    const float* out_b1 = (const float*)d_in[23];
    const float* out_w2 = (const float*)d_in[24];
    const float* out_b2 = (const float*)d_in[25];

    char* ws = (char*)d_ws;
    float* h     = (float*)(ws + O_H);
    float* delta = (float*)(ws + O_DELTA);
    float* xg    = (float*)(ws + O_XG);
    float* agg3  = (float*)(ws + O_AGG);
    float* Wbuf  = (float*)(ws + O_W);
    int* ip    = (int*)(ws + O_INT);
    int* deg   = ip + I_DEG;
    int* cur   = ip + I_CUR;
    int* cdeg  = ip + I_CDEG;
    int* ccur  = ip + I_CCUR;
    int* ibase = ip + I_BASE;
    int* cbase = ip + I_CBASE;
    int* csr   = ip + I_CSR;
    int* ccsr  = ip + I_CCSR;

    // zero the counters (ws is re-poisoned to 0xAA before every launch)
    hipMemsetAsync(ip, 0, (size_t)I_ZEND * sizeof(int), stream);

    k_init_h<<<(NN * 64 + 255) / 256, 256, 0, stream>>>(sites, sites_p, emb_w, emb_p_w, h);
    k_deg<<<(ET + 255) / 256, 256, 0, stream>>>(ei1, ei2, ei3, c1, c2, c3, deg, cdeg);
    k_scan<<<3, 256, 0, stream>>>(deg, ibase, cdeg, cbase);
    k_fill<<<(ET + 255) / 256, 256, 0, stream>>>(ei1, ei2, ei3, c1, c2, c3,
                                                 ibase, cur, csr, cbase, ccur, ccsr);

    for (int l = 0; l < L; l++) {
        k_edge_mlp<<<4 * BPC, 256, 0, stream>>>(ccsr, cbase, ew1, ew2, ew3,
                                                mlp_w1, mlp_b1, mlp_w2, mlp_b2, Wbuf, l);
        k_lin1<<<3 * X_WPG / 4, 256, 0, stream>>>(h, conv_w1, xg, l);
        k_agg<<<3 * AT / 4, 256, 0, stream>>>(csr, ibase, ei1, ei2, ei3, xg, Wbuf, agg3);
        for (int g = 0; g < 3; g++) {
            k_node2<<<NN / N2_ROWS / 4, 256, 0, stream>>>(agg3, conv_w2, conv_b2,
                                                          blk_w, blk_b, delta, h, l, g);
        }
    }
    k_read<<<BS, 256, 0, stream>>>(h, out_w1, out_b1, out_w2, out_b2, (float*)d_out);
}

// Round 2
// 2123.059 us; speedup vs baseline: 1.5126x; 1.5126x over previous
//
#include <hip/hip_runtime.h>
#include <math.h>

// ---------------- problem constants ----------------
constexpr int M1 = 2000, M2 = 400, BS = 8;
constexpr int AT = M1 + M2;            // 2400
constexpr int NN = BS * AT;            // 19200 nodes
constexpr int E1 = 60000, E2 = 20000, E3 = 20000;
constexpr int ET = E1 + E2 + E3;       // 100000
constexpr int H = 64, F = 64, NG = 50, L = 4, C = 4;
constexpr float CUTOFF = 10.0f;
constexpr float LOG2F_ = 0.6931471805599453f;

constexpr float SMEAR_STEP = 10.0f / 49.0f;
constexpr float SMEAR_COEFF = -12.005f;
constexpr float PI_OVER_CUT = 0.31415926535897932f; // pi/10

constexpr int NBLK = (ET + 255) / 256;  // 391 blocks in count/fill passes
constexpr int NBUCK = 12;               // (graph,color) buckets

// ---------------- workspace layout (bytes) ----------------
constexpr size_t O_H     = 0;                         // h      [NN,64] f32
constexpr size_t O_DELTA = O_H     + (size_t)NN * 64 * 4;
constexpr size_t O_XG    = O_DELTA + (size_t)NN * 64 * 4;   // xg [3,NN,64]
constexpr size_t O_AGG   = O_XG    + (size_t)3 * NN * 64 * 4; // agg3 [3,NN,64]
constexpr size_t O_W     = O_AGG   + (size_t)3 * NN * 64 * 4; // W  [ET,64]
constexpr size_t O_INT   = O_W     + (size_t)ET * 64 * 4;
// int region (element offsets from O_INT):
constexpr int I_DEG   = 0;          // [3*AT]   (zeroed)
constexpr int I_CUR   = 7200;       // [3*AT]   (zeroed)
constexpr int I_ZEND  = 14400;      // end of zeroed region
constexpr int I_BASE  = 14400;      // [3*(AT+1)] pad to 7204
constexpr int I_CBASE = 21604;      // [16] (15 used)
constexpr int I_CSR   = 21620;      // [ET]
constexpr int I_CCSR  = 121620;     // [ET]
constexpr int I_LRANK = 221620;     // [ET]  local rank within (block,bucket)
constexpr int I_BCNT  = 321620;     // [NBLK*12] per-block bucket counts
constexpr int I_BBASE = 326312;     // [NBLK*12] per-block bucket bases

__device__ inline float sspf(float x) {
    // shifted softplus: log(1+exp(x)) - log(2), numerically stable
    return fmaxf(x, 0.0f) + log1pf(expf(-fabsf(x))) - LOG2F_;
}

__device__ inline int graph_off(int g) { return g == 0 ? 0 : (g == 1 ? E1 : E1 + E2); }

__device__ inline void edge_decode(int idx, int& g, int& e,
                                   const int* ei1, const int* ei2, const int* ei3,
                                   const int* c1, const int* c2, const int* c3,
                                   const int*& ei, const int*& cl) {
    if (idx < E1)            { g = 0; e = idx;           ei = ei1; cl = c1; }
    else if (idx < E1 + E2)  { g = 1; e = idx - E1;      ei = ei2; cl = c2; }
    else                     { g = 2; e = idx - E1 - E2; ei = ei3; cl = c3; }
}

// ---------------- setup kernels ----------------
__global__ void k_init_h(const int* __restrict__ sites, const int* __restrict__ sites_p,
                         const float* __restrict__ emb_w, const float* __restrict__ emb_p_w,
                         float* __restrict__ h) {
    int idx = blockIdx.x * blockDim.x + threadIdx.x;
    if (idx >= NN * 64) return;
    int f = idx & 63;
    int n = idx >> 6;
    int b = n / AT;
    int i = n - b * AT;
    float v;
    if (i < M1) v = emb_w[sites[b * M1 + i] * H + f];
    else        v = emb_p_w[sites_p[b * M2 + (i - M1)] * H + f];
    h[idx] = v;
}

// Pass A: dst-degree atomics (7200 spread addresses, low contention) +
// per-block LDS color histogram (no contended global atomics).
__global__ void k_count(const int* __restrict__ ei1, const int* __restrict__ ei2,
                        const int* __restrict__ ei3, const int* __restrict__ c1,
                        const int* __restrict__ c2, const int* __restrict__ c3,
                        int* __restrict__ deg, int* __restrict__ bcnt,
                        int* __restrict__ lrank) {
    __shared__ int hist[NBUCK];
    int t = threadIdx.x;
    int idx = blockIdx.x * blockDim.x + t;
    if (t < NBUCK) hist[t] = 0;
    __syncthreads();
    if (idx < ET) {
        int g, e; const int* ei; const int* cl;
        edge_decode(idx, g, e, ei1, ei2, ei3, c1, c2, c3, ei, cl);
        atomicAdd(&deg[g * AT + ei[2 * e + 1]], 1);
        int bucket = g * 4 + cl[e];
        lrank[idx] = atomicAdd(&hist[bucket], 1);   // LDS atomic: cycles, not µs
    }
    __syncthreads();
    if (t < NBUCK) bcnt[blockIdx.x * NBUCK + t] = hist[t];
}

// Blocks 0..2: exclusive scan of deg[g] -> base[g].
// Block 3: per-bucket exclusive scan of bcnt over blocks -> bbase, cbase.
__global__ void k_scan(const int* __restrict__ deg, int* __restrict__ base,
                       const int* __restrict__ bcnt, int* __restrict__ bbase,
                       int* __restrict__ cbase) {
    const int T = 256, CH = 10; // 2560 >= 2400
    int t = threadIdx.x;
    if (blockIdx.x < 3) {
        __shared__ int lsum[T];
        int g = blockIdx.x;
        int loc[CH];
        int s = 0;
        #pragma unroll
        for (int i = 0; i < CH; i++) {
            int idx = t * CH + i;
            int v = (idx < AT) ? deg[g * AT + idx] : 0;
            loc[i] = s;
            s += v;
        }
        lsum[t] = s;
        __syncthreads();
        for (int off = 1; off < T; off <<= 1) {
            int v = 0;
            if (t >= off) v = lsum[t - off];
            __syncthreads();
            lsum[t] += v;
            __syncthreads();
        }
        int tb = lsum[t] - s; // exclusive prefix for this thread
        #pragma unroll
        for (int i = 0; i < CH; i++) {
            int idx = t * CH + i;
            if (idx < AT) base[g * (AT + 1) + idx] = tb + loc[i];
        }
        if (t == T - 1) base[g * (AT + 1) + AT] = lsum[T - 1];
    } else {
        // bucket scan: wave wv handles buckets wv, 4+wv, 8+wv
        __shared__ int tot[NBUCK];
        __shared__ int cb[NBUCK];
        int wv = t >> 6, lane = t & 63;
        int myTot[3];
        #pragma unroll
        for (int bi = 0; bi < 3; bi++) {
            int b = wv + bi * 4;
            int run = 0;
            for (int k0 = 0; k0 < NBLK; k0 += 64) {
                int k = k0 + lane;
                int v = (k < NBLK) ? bcnt[k * NBUCK + b] : 0;
                int s = v;
                #pragma unroll
                for (int off = 1; off < 64; off <<= 1) {
                    int u = __shfl_up(s, off);
                    if (lane >= off) s += u;
                }
                if (k < NBLK) bbase[k * NBUCK + b] = run + s - v; // exclusive, rel.
                run += __shfl(s, 63);
            }
            myTot[bi] = run;
            if (lane == 0) tot[b] = run;
        }
        (void)myTot;
        __syncthreads();
        if (t == 0) {
            for (int g = 0; g < 3; g++) {
                int run = graph_off(g);
                for (int c = 0; c < C; c++) {
                    cb[g * 4 + c] = run;
                    cbase[g * 5 + c] = run;
                    run += tot[g * 4 + c];
                }
                cbase[g * 5 + C] = run;
            }
        }
        __syncthreads();
        #pragma unroll
        for (int bi = 0; bi < 3; bi++) {
            int b = wv + bi * 4;
            int add = cb[b];
            for (int k0 = 0; k0 < NBLK; k0 += 64) {
                int k = k0 + lane;
                if (k < NBLK) bbase[k * NBUCK + b] += add;
            }
        }
    }
}

// Pass C: fill dst-CSR (cur atomics, spread) and color-CSR (no atomics).
__global__ void k_fill(const int* __restrict__ ei1, const int* __restrict__ ei2,
                       const int* __restrict__ ei3, const int* __restrict__ c1,
                       const int* __restrict__ c2, const int* __restrict__ c3,
                       const int* __restrict__ base, int* __restrict__ cur,
                       int* __restrict__ csr, const int* __restrict__ bbase,
                       const int* __restrict__ lrank, int* __restrict__ ccsr) {
    int idx = blockIdx.x * blockDim.x + threadIdx.x;
    if (idx >= ET) return;
    int g, e; const int* ei; const int* cl;
    edge_decode(idx, g, e, ei1, ei2, ei3, c1, c2, c3, ei, cl);
    int dst = ei[2 * e + 1];
    int p = base[g * (AT + 1) + dst] + atomicAdd(&cur[g * AT + dst], 1);
    csr[graph_off(g) + p] = e;
    int bucket = g * 4 + cl[e];
    int q = bbase[blockIdx.x * NBUCK + bucket] + lrank[idx];
    ccsr[q] = e;
}

// ---------------- per-layer kernels ----------------
// Edge MLP: W[e][f] = (ssp(attr@w1[c]+b1[c]) @ w2[c] + b2[c]) * Ccut
// One wave per edge-chunk, edges pre-sorted by (g,color); weight columns in VGPRs.
constexpr int EW_CH = 32;                       // edges per wave
constexpr int B1G = (E1 + 4 * EW_CH - 1) / (4 * EW_CH); // 469
constexpr int B2G = (E2 + 4 * EW_CH - 1) / (4 * EW_CH); // 157
constexpr int B3G = (E3 + 4 * EW_CH - 1) / (4 * EW_CH); // 157
constexpr int BPC = B1G + B2G + B3G;            // 783 blocks per color

__global__ __launch_bounds__(256) void k_edge_mlp(
    const int* __restrict__ ccsr, const int* __restrict__ cbase,
    const float* __restrict__ ew1, const float* __restrict__ ew2,
    const float* __restrict__ ew3,
    const float* __restrict__ mlp_w1, const float* __restrict__ mlp_b1,
    const float* __restrict__ mlp_w2, const float* __restrict__ mlp_b2,
    float* __restrict__ Wout, int l) {
    const int lane = threadIdx.x & 63;
    const int wv = threadIdx.x >> 6;
    int bid = blockIdx.x;
    int c = bid / BPC;
    int r = bid - c * BPC;
    int g, blk;
    if (r < B1G)            { g = 0; blk = r; }
    else if (r < B1G + B2G) { g = 1; blk = r - B1G; }
    else                    { g = 2; blk = r - B1G - B2G; }
    int rbase = cbase[g * 5 + c], rend = cbase[g * 5 + c + 1];
    int s = rbase + (blk * 4 + wv) * EW_CH;
    if (s >= rend) return;
    int e_hi = min(s + EW_CH, rend);
    const float* ew = (g == 0) ? ew1 : (g == 1 ? ew2 : ew3);
    int goff = graph_off(g);
    size_t wb = (size_t)((l * 3 + g) * C + c);
    const float* w1 = mlp_w1 + wb * NG * F;
    const float* w2 = mlp_w2 + wb * F * F;
    float w1c[NG], w2c[F];
    #pragma unroll
    for (int k = 0; k < NG; k++) w1c[k] = w1[k * F + lane];
    #pragma unroll
    for (int k = 0; k < F; k++) w2c[k] = w2[k * F + lane];
    float b1c = mlp_b1[wb * F + lane];
    float b2c = mlp_b2[wb * F + lane];
    float off = (float)lane * SMEAR_STEP;
    for (int i = s; i < e_hi; i++) {
        int eid = ccsr[i];
        float d = ew[eid];
        float dd = d - off;
        float av = (lane < NG) ? expf(SMEAR_COEFF * dd * dd) : 0.0f;
        float acc = b1c;
        #pragma unroll
        for (int k = 0; k < NG; k++) acc = fmaf(__shfl(av, k), w1c[k], acc);
        float t = sspf(acc);
        float acc2 = b2c;
        #pragma unroll
        for (int j = 0; j < F; j++) acc2 = fmaf(__shfl(t, j), w2c[j], acc2);
        float ccut = 0.5f * (cosf(d * PI_OVER_CUT) + 1.0f);
        Wout[(size_t)(goff + eid) * F + lane] = acc2 * ccut;
    }
}

// x_g = h @ conv_w1[l,g]  (no bias), for all 3 graphs
constexpr int X_ROWS = 16;
constexpr int X_WPG = NN / X_ROWS;  // 1200 waves per graph
__global__ __launch_bounds__(256) void k_lin1(
    const float* __restrict__ h, const float* __restrict__ conv_w1,
    float* __restrict__ xg, int l) {
    const int lane = threadIdx.x & 63;
    int w = blockIdx.x * 4 + (threadIdx.x >> 6);
    int g = w / X_WPG;
    int rw = w - g * X_WPG;
    const float* wm = conv_w1 + (size_t)(l * 3 + g) * H * F;
    float wc[H];
    #pragma unroll
    for (int k = 0; k < H; k++) wc[k] = wm[k * F + lane];
    float* xo = xg + (size_t)g * NN * F;
    int r0 = rw * X_ROWS;
    for (int r = r0; r < r0 + X_ROWS; r++) {
        float hv = h[(size_t)r * H + lane];
        float acc = 0.0f;
        #pragma unroll
        for (int k = 0; k < H; k++) acc = fmaf(__shfl(hv, k), wc[k], acc);
        xo[(size_t)r * F + lane] = acc;
    }
}

// Aggregation: one wave per (g,dst), all 8 batches accumulated in registers.
__global__ __launch_bounds__(256) void k_agg(
    const int* __restrict__ csr, const int* __restrict__ base,
    const int* __restrict__ ei1, const int* __restrict__ ei2,
    const int* __restrict__ ei3,
    const float* __restrict__ xg, const float* __restrict__ Wm,
    float* __restrict__ agg3) {
    const int lane = threadIdx.x & 63;
    int w = blockIdx.x * 4 + (threadIdx.x >> 6); // 0..7199
    int g = w / AT;
    int dst = w - g * AT;
    const int* ei = (g == 0) ? ei1 : (g == 1 ? ei2 : ei3);
    int goff = graph_off(g);
    int s = base[g * (AT + 1) + dst];
    int e = base[g * (AT + 1) + dst + 1];
    float acc[BS];
    #pragma unroll
    for (int b = 0; b < BS; b++) acc[b] = 0.0f;
    for (int i = s; i < e; i++) {
        int eid = csr[goff + i];
        int src = ei[2 * eid];
        float wv = Wm[(size_t)(goff + eid) * F + lane];
        const float* xb = xg + ((size_t)g * NN + src) * F + lane;
        #pragma unroll
        for (int b = 0; b < BS; b++)
            acc[b] = fmaf(xb[(size_t)b * AT * F], wv, acc[b]);
    }
    float* ao = agg3 + ((size_t)g * NN + dst) * F + lane;
    #pragma unroll
    for (int b = 0; b < BS; b++) ao[(size_t)b * AT * F] = acc[b];
}

// lin2 + ssp + block-linear, accumulate delta; g==2 folds h += delta
constexpr int N2_ROWS = 8;
__global__ __launch_bounds__(256) void k_node2(
    const float* __restrict__ agg3, const float* __restrict__ conv_w2,
    const float* __restrict__ conv_b2, const float* __restrict__ blk_w,
    const float* __restrict__ blk_b, float* __restrict__ delta,
    float* __restrict__ h, int l, int g) {
    const int lane = threadIdx.x & 63;
    int w = blockIdx.x * 4 + (threadIdx.x >> 6);
    size_t pb = (size_t)(l * 3 + g);
    const float* cw2 = conv_w2 + pb * F * H;
    const float* bw = blk_w + pb * H * H;
    float c2c[F], bwc[H];
    #pragma unroll
    for (int k = 0; k < F; k++) c2c[k] = cw2[k * H + lane];
    #pragma unroll
    for (int k = 0; k < H; k++) bwc[k] = bw[k * H + lane];
    float cb2c = conv_b2[pb * H + lane];
    float bbc = blk_b[pb * H + lane];
    const float* ag = agg3 + (size_t)g * NN * F;
    int r0 = w * N2_ROWS;
    for (int r = r0; r < r0 + N2_ROWS; r++) {
        float av = ag[(size_t)r * F + lane];
        float acc = cb2c;
        #pragma unroll
        for (int k = 0; k < F; k++) acc = fmaf(__shfl(av, k), c2c[k], acc);
        float t = sspf(acc);
        float o = bbc;
        #pragma unroll
        for (int j = 0; j < H; j++) o = fmaf(__shfl(t, j), bwc[j], o);
        size_t ix = (size_t)r * H + lane;
        if (g == 0)      delta[ix] = o;
        else if (g == 1) delta[ix] += o;
        else             h[ix] += delta[ix] + o;
    }
}

// Readout: o[b] = sum_pore h . weff + M2*(b1.W2 + b2), weff = W1@W2
__global__ void k_read(const float* __restrict__ h,
                       const float* __restrict__ w1, const float* __restrict__ b1,
                       const float* __restrict__ w2, const float* __restrict__ b2,
                       float* __restrict__ out) {
    int b = blockIdx.x;
    int lane = threadIdx.x & 63;
    int wv = threadIdx.x >> 6;
    __shared__ float part[4];
    float weff = 0.0f;
    #pragma unroll
    for (int j = 0; j < H / 2; j++) weff = fmaf(w1[lane * (H / 2) + j], w2[j], weff);
    float acc = 0.0f;
    for (int i = wv * (M2 / 4); i < (wv + 1) * (M2 / 4); i++)
        acc += h[((size_t)b * AT + M1 + i) * H + lane];
    float v = acc * weff;
    for (int off = 32; off; off >>= 1) v += __shfl_xor(v, off);
    if (lane == 0) part[wv] = v;
    __syncthreads();
    if (threadIdx.x == 0) {
        float bias = b2[0];
        for (int j = 0; j < H / 2; j++) bias = fmaf(b1[j], w2[j], bias);
        out[b] = part[0] + part[1] + part[2] + part[3] + (float)M2 * bias;
    }
}

// ---------------- launcher ----------------
extern "C" void kernel_launch(void* const* d_in, const int* in_sizes, int n_in,
                              void* d_out, int out_size, void* d_ws, size_t ws_size,
                              hipStream_t stream) {
    const int* sites   = (const int*)d_in[0];
    const int* sites_p = (const int*)d_in[1];
    const int* ei1 = (const int*)d_in[2];
    const float* ew1 = (const float*)d_in[3];
    const int* c1 = (const int*)d_in[4];
    const int* ei2 = (const int*)d_in[5];
    const float* ew2 = (const float*)d_in[6];
    const int* c2 = (const int*)d_in[7];
    const int* ei3 = (const int*)d_in[8];
    const float* ew3 = (const float*)d_in[9];
    const int* c3 = (const int*)d_in[10];
    const float* emb_w   = (const float*)d_in[11];
    const float* emb_p_w = (const float*)d_in[12];
    const float* mlp_w1 = (const float*)d_in[13];
    const float* mlp_b1 = (const float*)d_in[14];
    const float* mlp_w2 = (const float*)d_in[15];
    const float* mlp_b2 = (const float*)d_in[16];
    const float* conv_w1 = (const float*)d_in[17];
    const float* conv_w2 = (const float*)d_in[18];
    const float* conv_b2 = (const float*)d_in[19];
    const float* blk_w = (const float*)d_in[20];
    const float* blk_b = (const float*)d_in[21];
    const float* out_w1 = (const float*)d_in[22];
    const float* out_b1 = (const float*)d_in[23];
    const float* out_w2 = (const float*)d_in[24];
    const float* out_b2 = (const float*)d_in[25];

    char* ws = (char*)d_ws;
    float* h     = (float*)(ws + O_H);
    float* delta = (float*)(ws + O_DELTA);
    float* xg    = (float*)(ws + O_XG);
    float* agg3  = (float*)(ws + O_AGG);
    float* Wbuf  = (float*)(ws + O_W);
    int* ip    = (int*)(ws + O_INT);
    int* deg   = ip + I_DEG;
    int* cur   = ip + I_CUR;
    int* ibase = ip + I_BASE;
    int* cbase = ip + I_CBASE;
    int* csr   = ip + I_CSR;
    int* ccsr  = ip + I_CCSR;
    int* lrank = ip + I_LRANK;
    int* bcnt  = ip + I_BCNT;
    int* bbase = ip + I_BBASE;

    // zero the counters (ws is re-poisoned to 0xAA before every launch)
    hipMemsetAsync(ip, 0, (size_t)I_ZEND * sizeof(int), stream);

    k_init_h<<<(NN * 64 + 255) / 256, 256, 0, stream>>>(sites, sites_p, emb_w, emb_p_w, h);
    k_count<<<NBLK, 256, 0, stream>>>(ei1, ei2, ei3, c1, c2, c3, deg, bcnt, lrank);
    k_scan<<<4, 256, 0, stream>>>(deg, ibase, bcnt, bbase, cbase);
    k_fill<<<NBLK, 256, 0, stream>>>(ei1, ei2, ei3, c1, c2, c3,
                                     ibase, cur, csr, bbase, lrank, ccsr);

    for (int l = 0; l < L; l++) {
        k_edge_mlp<<<4 * BPC, 256, 0, stream>>>(ccsr, cbase, ew1, ew2, ew3,
                                                mlp_w1, mlp_b1, mlp_w2, mlp_b2, Wbuf, l);
        k_lin1<<<3 * X_WPG / 4, 256, 0, stream>>>(h, conv_w1, xg, l);
        k_agg<<<3 * AT / 4, 256, 0, stream>>>(csr, ibase, ei1, ei2, ei3, xg, Wbuf, agg3);
        for (int g = 0; g < 3; g++) {
            k_node2<<<NN / N2_ROWS / 4, 256, 0, stream>>>(agg3, conv_w2, conv_b2,
                                                          blk_w, blk_b, delta, h, l, g);
        }
    }
    k_read<<<BS, 256, 0, stream>>>(h, out_w1, out_b1, out_w2, out_b2, (float*)d_out);
}

// Round 3
// 1508.086 us; speedup vs baseline: 2.1294x; 1.4078x over previous
//
#include <hip/hip_runtime.h>
#include <math.h>

// ---------------- problem constants ----------------
constexpr int M1 = 2000, M2 = 400, BS = 8;
constexpr int AT = M1 + M2;            // 2400
constexpr int NN = BS * AT;            // 19200 nodes
constexpr int E1 = 60000, E2 = 20000, E3 = 20000;
constexpr int ET = E1 + E2 + E3;       // 100000
constexpr int H = 64, F = 64, NG = 50, L = 4, C = 4;
constexpr float CUTOFF = 10.0f;
constexpr float LOG2F_ = 0.6931471805599453f;

constexpr float SMEAR_STEP = 10.0f / 49.0f;
constexpr float SMEAR_COEFF = -12.005f;
constexpr float PI_OVER_CUT = 0.31415926535897932f; // pi/10

constexpr int NBLK = (ET + 255) / 256;  // 391 blocks in count/fill passes
constexpr int NBUCK = 12;               // (graph,color) buckets

// ---------------- workspace layout (bytes) ----------------
constexpr size_t O_H     = 0;                         // h      [NN,64] f32
constexpr size_t O_DELTA = O_H     + (size_t)NN * 64 * 4;
constexpr size_t O_XG    = O_DELTA + (size_t)NN * 64 * 4;   // xg [3,NN,64]
constexpr size_t O_AGG   = O_XG    + (size_t)3 * NN * 64 * 4; // agg3 [3,NN,64]
constexpr size_t O_W     = O_AGG   + (size_t)3 * NN * 64 * 4; // W  [ET,64]
constexpr size_t O_INT   = O_W     + (size_t)ET * 64 * 4;
// int region (element offsets from O_INT):
constexpr int I_DEG   = 0;          // [3*AT]   (zeroed)
constexpr int I_CUR   = 7200;       // [3*AT]   (zeroed)
constexpr int I_ZEND  = 14400;      // end of zeroed region
constexpr int I_BASE  = 14400;      // [3*(AT+1)] pad to 7204
constexpr int I_CBASE = 21604;      // [16] (15 used)
constexpr int I_CSR   = 21620;      // [ET]
constexpr int I_CCSR  = 121620;     // [ET]
constexpr int I_LRANK = 221620;     // [ET]  local rank within (block,bucket)
constexpr int I_BCNT  = 321620;     // [NBLK*12] per-block bucket counts
constexpr int I_BBASE = 326312;     // [NBLK*12] per-block bucket bases

__device__ inline float sspf(float x) {
    // shifted softplus: log(1+exp(x)) - log(2), numerically stable
    return fmaxf(x, 0.0f) + log1pf(expf(-fabsf(x))) - LOG2F_;
}

// fast variant for the edge MLP (error ~1e-6 abs, threshold is ~1.1)
__device__ inline float sspf_fast(float x) {
    float t = __expf(-fabsf(x));
    return fmaxf(x, 0.0f) + __logf(1.0f + t) - LOG2F_;
}

__device__ inline int graph_off(int g) { return g == 0 ? 0 : (g == 1 ? E1 : E1 + E2); }

__device__ inline void edge_decode(int idx, int& g, int& e,
                                   const int* ei1, const int* ei2, const int* ei3,
                                   const int* c1, const int* c2, const int* c3,
                                   const int*& ei, const int*& cl) {
    if (idx < E1)            { g = 0; e = idx;           ei = ei1; cl = c1; }
    else if (idx < E1 + E2)  { g = 1; e = idx - E1;      ei = ei2; cl = c2; }
    else                     { g = 2; e = idx - E1 - E2; ei = ei3; cl = c3; }
}

// ---------------- setup kernels ----------------
__global__ void k_init_h(const int* __restrict__ sites, const int* __restrict__ sites_p,
                         const float* __restrict__ emb_w, const float* __restrict__ emb_p_w,
                         float* __restrict__ h) {
    int idx = blockIdx.x * blockDim.x + threadIdx.x;
    if (idx >= NN * 64) return;
    int f = idx & 63;
    int n = idx >> 6;
    int b = n / AT;
    int i = n - b * AT;
    float v;
    if (i < M1) v = emb_w[sites[b * M1 + i] * H + f];
    else        v = emb_p_w[sites_p[b * M2 + (i - M1)] * H + f];
    h[idx] = v;
}

// Pass A: dst-degree atomics (7200 spread addresses, low contention) +
// per-block LDS color histogram (no contended global atomics).
__global__ void k_count(const int* __restrict__ ei1, const int* __restrict__ ei2,
                        const int* __restrict__ ei3, const int* __restrict__ c1,
                        const int* __restrict__ c2, const int* __restrict__ c3,
                        int* __restrict__ deg, int* __restrict__ bcnt,
                        int* __restrict__ lrank) {
    __shared__ int hist[NBUCK];
    int t = threadIdx.x;
    int idx = blockIdx.x * blockDim.x + t;
    if (t < NBUCK) hist[t] = 0;
    __syncthreads();
    if (idx < ET) {
        int g, e; const int* ei; const int* cl;
        edge_decode(idx, g, e, ei1, ei2, ei3, c1, c2, c3, ei, cl);
        atomicAdd(&deg[g * AT + ei[2 * e + 1]], 1);
        int bucket = g * 4 + cl[e];
        lrank[idx] = atomicAdd(&hist[bucket], 1);   // LDS atomic: cycles, not µs
    }
    __syncthreads();
    if (t < NBUCK) bcnt[blockIdx.x * NBUCK + t] = hist[t];
}

// Blocks 0..2: exclusive scan of deg[g] -> base[g].
// Block 3: per-bucket exclusive scan of bcnt over blocks -> bbase, cbase.
__global__ void k_scan(const int* __restrict__ deg, int* __restrict__ base,
                       const int* __restrict__ bcnt, int* __restrict__ bbase,
                       int* __restrict__ cbase) {
    const int T = 256, CH = 10; // 2560 >= 2400
    int t = threadIdx.x;
    if (blockIdx.x < 3) {
        __shared__ int lsum[T];
        int g = blockIdx.x;
        int loc[CH];
        int s = 0;
        #pragma unroll
        for (int i = 0; i < CH; i++) {
            int idx = t * CH + i;
            int v = (idx < AT) ? deg[g * AT + idx] : 0;
            loc[i] = s;
            s += v;
        }
        lsum[t] = s;
        __syncthreads();
        for (int off = 1; off < T; off <<= 1) {
            int v = 0;
            if (t >= off) v = lsum[t - off];
            __syncthreads();
            lsum[t] += v;
            __syncthreads();
        }
        int tb = lsum[t] - s; // exclusive prefix for this thread
        #pragma unroll
        for (int i = 0; i < CH; i++) {
            int idx = t * CH + i;
            if (idx < AT) base[g * (AT + 1) + idx] = tb + loc[i];
        }
        if (t == T - 1) base[g * (AT + 1) + AT] = lsum[T - 1];
    } else {
        // bucket scan: wave wv handles buckets wv, 4+wv, 8+wv
        __shared__ int tot[NBUCK];
        __shared__ int cb[NBUCK];
        int wv = t >> 6, lane = t & 63;
        #pragma unroll
        for (int bi = 0; bi < 3; bi++) {
            int b = wv + bi * 4;
            int run = 0;
            for (int k0 = 0; k0 < NBLK; k0 += 64) {
                int k = k0 + lane;
                int v = (k < NBLK) ? bcnt[k * NBUCK + b] : 0;
                int s = v;
                #pragma unroll
                for (int off = 1; off < 64; off <<= 1) {
                    int u = __shfl_up(s, off);
                    if (lane >= off) s += u;
                }
                if (k < NBLK) bbase[k * NBUCK + b] = run + s - v; // exclusive, rel.
                run += __shfl(s, 63);
            }
            if (lane == 0) tot[b] = run;
        }
        __syncthreads();
        if (t == 0) {
            for (int g = 0; g < 3; g++) {
                int run = graph_off(g);
                for (int c = 0; c < C; c++) {
                    cb[g * 4 + c] = run;
                    cbase[g * 5 + c] = run;
                    run += tot[g * 4 + c];
                }
                cbase[g * 5 + C] = run;
            }
        }
        __syncthreads();
        #pragma unroll
        for (int bi = 0; bi < 3; bi++) {
            int b = wv + bi * 4;
            int add = cb[b];
            for (int k0 = 0; k0 < NBLK; k0 += 64) {
                int k = k0 + lane;
                if (k < NBLK) bbase[k * NBUCK + b] += add;
            }
        }
    }
}

// Pass C: fill dst-CSR (cur atomics, spread) and color-CSR (no atomics).
__global__ void k_fill(const int* __restrict__ ei1, const int* __restrict__ ei2,
                       const int* __restrict__ ei3, const int* __restrict__ c1,
                       const int* __restrict__ c2, const int* __restrict__ c3,
                       const int* __restrict__ base, int* __restrict__ cur,
                       int* __restrict__ csr, const int* __restrict__ bbase,
                       const int* __restrict__ lrank, int* __restrict__ ccsr) {
    int idx = blockIdx.x * blockDim.x + threadIdx.x;
    if (idx >= ET) return;
    int g, e; const int* ei; const int* cl;
    edge_decode(idx, g, e, ei1, ei2, ei3, c1, c2, c3, ei, cl);
    int dst = ei[2 * e + 1];
    int p = base[g * (AT + 1) + dst] + atomicAdd(&cur[g * AT + dst], 1);
    csr[graph_off(g) + p] = e;
    int bucket = g * 4 + cl[e];
    int q = bbase[blockIdx.x * NBUCK + bucket] + lrank[idx];
    ccsr[q] = e;
}

// ---------------- per-layer kernels ----------------
// Edge MLP, edge-per-lane: each lane computes one edge's full 50->64->64 MLP.
// Weights are wave-uniform (edges bucketed by (g,color)) -> SGPR operands,
// zero shuffles, zero LDS. All loops fully unrolled so attr/hmid stay in VGPRs.
constexpr int EW_CH = 64;                       // edges per wave (1 per lane)
constexpr int B1G = (E1 + 4 * EW_CH - 1) / (4 * EW_CH); // 235
constexpr int B2G = (E2 + 4 * EW_CH - 1) / (4 * EW_CH); // 79
constexpr int B3G = (E3 + 4 * EW_CH - 1) / (4 * EW_CH); // 79
constexpr int BPC = B1G + B2G + B3G;            // 393 blocks per color

__global__ __launch_bounds__(256) void k_edge_mlp(
    const int* __restrict__ ccsr, const int* __restrict__ cbase,
    const float* __restrict__ ew1, const float* __restrict__ ew2,
    const float* __restrict__ ew3,
    const float* __restrict__ mlp_w1, const float* __restrict__ mlp_b1,
    const float* __restrict__ mlp_w2, const float* __restrict__ mlp_b2,
    float* __restrict__ Wout, int l) {
    const int lane = threadIdx.x & 63;
    const int wv = threadIdx.x >> 6;
    int bid = blockIdx.x;
    int c = bid / BPC;
    int r = bid - c * BPC;
    int g, blk;
    if (r < B1G)            { g = 0; blk = r; }
    else if (r < B1G + B2G) { g = 1; blk = r - B1G; }
    else                    { g = 2; blk = r - B1G - B2G; }
    int rbase = cbase[g * 5 + c], rend = cbase[g * 5 + c + 1];
    int s = rbase + (blk * 4 + wv) * EW_CH;
    if (s >= rend) return;
    bool valid = (s + lane) < rend;
    int eid = ccsr[min(s + lane, rend - 1)];
    const float* ew = (g == 0) ? ew1 : (g == 1 ? ew2 : ew3);
    int goff = graph_off(g);
    float d = ew[eid];

    size_t wb = (size_t)((l * 3 + g) * C + c);
    const float* w1 = mlp_w1 + wb * NG * F;
    const float* w2 = mlp_w2 + wb * F * F;
    const float* b1 = mlp_b1 + wb * F;
    const float* b2 = mlp_b2 + wb * F;

    // Gaussian smearing (per-lane scalar d)
    float attr[NG];
    #pragma unroll
    for (int k = 0; k < NG; k++) {
        float dd = d - (float)k * SMEAR_STEP;
        attr[k] = __expf(SMEAR_COEFF * dd * dd);
    }

    // stage 1: hmid = ssp(attr @ w1 + b1), weights via SGPR
    float hmid[F];
    #pragma unroll
    for (int jt = 0; jt < F; jt += 16) {
        float acc[16];
        #pragma unroll
        for (int u = 0; u < 16; u++) acc[u] = b1[jt + u];
        #pragma unroll
        for (int k = 0; k < NG; k++) {
            float a = attr[k];
            #pragma unroll
            for (int u = 0; u < 16; u++)
                acc[u] = fmaf(a, w1[k * F + jt + u], acc[u]);
        }
        #pragma unroll
        for (int u = 0; u < 16; u++) hmid[jt + u] = sspf_fast(acc[u]);
    }

    float ccut = 0.5f * (__cosf(d * PI_OVER_CUT) + 1.0f);
    float* orow = Wout + (size_t)(goff + eid) * F;

    // stage 2: out = (hmid @ w2 + b2) * ccut, per-lane float4 row stores
    #pragma unroll
    for (int ft = 0; ft < F; ft += 16) {
        float acc[16];
        #pragma unroll
        for (int u = 0; u < 16; u++) acc[u] = b2[ft + u];
        #pragma unroll
        for (int j = 0; j < F; j++) {
            float hv = hmid[j];
            #pragma unroll
            for (int u = 0; u < 16; u++)
                acc[u] = fmaf(hv, w2[j * F + ft + u], acc[u]);
        }
        if (valid) {
            #pragma unroll
            for (int u = 0; u < 16; u += 4) {
                float4 v = make_float4(acc[u] * ccut, acc[u + 1] * ccut,
                                       acc[u + 2] * ccut, acc[u + 3] * ccut);
                *reinterpret_cast<float4*>(orow + ft + u) = v;
            }
        }
    }
}

// x_g = h @ conv_w1[l,g]  (no bias), for all 3 graphs
constexpr int X_ROWS = 16;
constexpr int X_WPG = NN / X_ROWS;  // 1200 waves per graph
__global__ __launch_bounds__(256) void k_lin1(
    const float* __restrict__ h, const float* __restrict__ conv_w1,
    float* __restrict__ xg, int l) {
    const int lane = threadIdx.x & 63;
    int w = blockIdx.x * 4 + (threadIdx.x >> 6);
    int g = w / X_WPG;
    int rw = w - g * X_WPG;
    const float* wm = conv_w1 + (size_t)(l * 3 + g) * H * F;
    float wc[H];
    #pragma unroll
    for (int k = 0; k < H; k++) wc[k] = wm[k * F + lane];
    float* xo = xg + (size_t)g * NN * F;
    int r0 = rw * X_ROWS;
    for (int r = r0; r < r0 + X_ROWS; r++) {
        float hv = h[(size_t)r * H + lane];
        float acc = 0.0f;
        #pragma unroll
        for (int k = 0; k < H; k++) acc = fmaf(__shfl(hv, k), wc[k], acc);
        xo[(size_t)r * F + lane] = acc;
    }
}

// Aggregation: one wave per (g,dst), all 8 batches accumulated in registers.
__global__ __launch_bounds__(256) void k_agg(
    const int* __restrict__ csr, const int* __restrict__ base,
    const int* __restrict__ ei1, const int* __restrict__ ei2,
    const int* __restrict__ ei3,
    const float* __restrict__ xg, const float* __restrict__ Wm,
    float* __restrict__ agg3) {
    const int lane = threadIdx.x & 63;
    int w = blockIdx.x * 4 + (threadIdx.x >> 6); // 0..7199
    int g = w / AT;
    int dst = w - g * AT;
    const int* ei = (g == 0) ? ei1 : (g == 1 ? ei2 : ei3);
    int goff = graph_off(g);
    int s = base[g * (AT + 1) + dst];
    int e = base[g * (AT + 1) + dst + 1];
    float acc[BS];
    #pragma unroll
    for (int b = 0; b < BS; b++) acc[b] = 0.0f;
    for (int i = s; i < e; i++) {
        int eid = csr[goff + i];
        int src = ei[2 * eid];
        float wv = Wm[(size_t)(goff + eid) * F + lane];
        const float* xb = xg + ((size_t)g * NN + src) * F + lane;
        #pragma unroll
        for (int b = 0; b < BS; b++)
            acc[b] = fmaf(xb[(size_t)b * AT * F], wv, acc[b]);
    }
    float* ao = agg3 + ((size_t)g * NN + dst) * F + lane;
    #pragma unroll
    for (int b = 0; b < BS; b++) ao[(size_t)b * AT * F] = acc[b];
}

// lin2 + ssp + block-linear, accumulate delta; g==2 folds h += delta
constexpr int N2_ROWS = 8;
__global__ __launch_bounds__(256) void k_node2(
    const float* __restrict__ agg3, const float* __restrict__ conv_w2,
    const float* __restrict__ conv_b2, const float* __restrict__ blk_w,
    const float* __restrict__ blk_b, float* __restrict__ delta,
    float* __restrict__ h, int l, int g) {
    const int lane = threadIdx.x & 63;
    int w = blockIdx.x * 4 + (threadIdx.x >> 6);
    size_t pb = (size_t)(l * 3 + g);
    const float* cw2 = conv_w2 + pb * F * H;
    const float* bw = blk_w + pb * H * H;
    float c2c[F], bwc[H];
    #pragma unroll
    for (int k = 0; k < F; k++) c2c[k] = cw2[k * H + lane];
    #pragma unroll
    for (int k = 0; k < H; k++) bwc[k] = bw[k * H + lane];
    float cb2c = conv_b2[pb * H + lane];
    float bbc = blk_b[pb * H + lane];
    const float* ag = agg3 + (size_t)g * NN * F;
    int r0 = w * N2_ROWS;
    for (int r = r0; r < r0 + N2_ROWS; r++) {
        float av = ag[(size_t)r * F + lane];
        float acc = cb2c;
        #pragma unroll
        for (int k = 0; k < F; k++) acc = fmaf(__shfl(av, k), c2c[k], acc);
        float t = sspf(acc);
        float o = bbc;
        #pragma unroll
        for (int j = 0; j < H; j++) o = fmaf(__shfl(t, j), bwc[j], o);
        size_t ix = (size_t)r * H + lane;
        if (g == 0)      delta[ix] = o;
        else if (g == 1) delta[ix] += o;
        else             h[ix] += delta[ix] + o;
    }
}

// Readout: o[b] = sum_pore h . weff + M2*(b1.W2 + b2), weff = W1@W2
__global__ void k_read(const float* __restrict__ h,
                       const float* __restrict__ w1, const float* __restrict__ b1,
                       const float* __restrict__ w2, const float* __restrict__ b2,
                       float* __restrict__ out) {
    int b = blockIdx.x;
    int lane = threadIdx.x & 63;
    int wv = threadIdx.x >> 6;
    __shared__ float part[4];
    float weff = 0.0f;
    #pragma unroll
    for (int j = 0; j < H / 2; j++) weff = fmaf(w1[lane * (H / 2) + j], w2[j], weff);
    float acc = 0.0f;
    for (int i = wv * (M2 / 4); i < (wv + 1) * (M2 / 4); i++)
        acc += h[((size_t)b * AT + M1 + i) * H + lane];
    float v = acc * weff;
    for (int off = 32; off; off >>= 1) v += __shfl_xor(v, off);
    if (lane == 0) part[wv] = v;
    __syncthreads();
    if (threadIdx.x == 0) {
        float bias = b2[0];
        for (int j = 0; j < H / 2; j++) bias = fmaf(b1[j], w2[j], bias);
        out[b] = part[0] + part[1] + part[2] + part[3] + (float)M2 * bias;
    }
}

// ---------------- launcher ----------------
extern "C" void kernel_launch(void* const* d_in, const int* in_sizes, int n_in,
                              void* d_out, int out_size, void* d_ws, size_t ws_size,
                              hipStream_t stream) {
    const int* sites   = (const int*)d_in[0];
    const int* sites_p = (const int*)d_in[1];
    const int* ei1 = (const int*)d_in[2];
    const float* ew1 = (const float*)d_in[3];
    const int* c1 = (const int*)d_in[4];
    const int* ei2 = (const int*)d_in[5];
    const float* ew2 = (const float*)d_in[6];
    const int* c2 = (const int*)d_in[7];
    const int* ei3 = (const int*)d_in[8];
    const float* ew3 = (const float*)d_in[9];
    const int* c3 = (const int*)d_in[10];
    const float* emb_w   = (const float*)d_in[11];
    const float* emb_p_w = (const float*)d_in[12];
    const float* mlp_w1 = (const float*)d_in[13];
    const float* mlp_b1 = (const float*)d_in[14];
    const float* mlp_w2 = (const float*)d_in[15];
    const float* mlp_b2 = (const float*)d_in[16];
    const float* conv_w1 = (const float*)d_in[17];
    const float* conv_w2 = (const float*)d_in[18];
    const float* conv_b2 = (const float*)d_in[19];
    const float* blk_w = (const float*)d_in[20];
    const float* blk_b = (const float*)d_in[21];
    const float* out_w1 = (const float*)d_in[22];
    const float* out_b1 = (const float*)d_in[23];
    const float* out_w2 = (const float*)d_in[24];
    const float* out_b2 = (const float*)d_in[25];

    char* ws = (char*)d_ws;
    float* h     = (float*)(ws + O_H);
    float* delta = (float*)(ws + O_DELTA);
    float* xg    = (float*)(ws + O_XG);
    float* agg3  = (float*)(ws + O_AGG);
    float* Wbuf  = (float*)(ws + O_W);
    int* ip    = (int*)(ws + O_INT);
    int* deg   = ip + I_DEG;
    int* cur   = ip + I_CUR;
    int* ibase = ip + I_BASE;
    int* cbase = ip + I_CBASE;
    int* csr   = ip + I_CSR;
    int* ccsr  = ip + I_CCSR;
    int* lrank = ip + I_LRANK;
    int* bcnt  = ip + I_BCNT;
    int* bbase = ip + I_BBASE;

    // zero the counters (ws is re-poisoned to 0xAA before every launch)
    hipMemsetAsync(ip, 0, (size_t)I_ZEND * sizeof(int), stream);

    k_init_h<<<(NN * 64 + 255) / 256, 256, 0, stream>>>(sites, sites_p, emb_w, emb_p_w, h);
    k_count<<<NBLK, 256, 0, stream>>>(ei1, ei2, ei3, c1, c2, c3, deg, bcnt, lrank);
    k_scan<<<4, 256, 0, stream>>>(deg, ibase, bcnt, bbase, cbase);
    k_fill<<<NBLK, 256, 0, stream>>>(ei1, ei2, ei3, c1, c2, c3,
                                     ibase, cur, csr, bbase, lrank, ccsr);

    for (int l = 0; l < L; l++) {
        k_edge_mlp<<<4 * BPC, 256, 0, stream>>>(ccsr, cbase, ew1, ew2, ew3,
                                                mlp_w1, mlp_b1, mlp_w2, mlp_b2, Wbuf, l);
        k_lin1<<<3 * X_WPG / 4, 256, 0, stream>>>(h, conv_w1, xg, l);
        k_agg<<<3 * AT / 4, 256, 0, stream>>>(csr, ibase, ei1, ei2, ei3, xg, Wbuf, agg3);
        for (int g = 0; g < 3; g++) {
            k_node2<<<NN / N2_ROWS / 4, 256, 0, stream>>>(agg3, conv_w2, conv_b2,
                                                          blk_w, blk_b, delta, h, l, g);
        }
    }
    k_read<<<BS, 256, 0, stream>>>(h, out_w1, out_b1, out_w2, out_b2, (float*)d_out);
}

// Round 4
// 1142.879 us; speedup vs baseline: 2.8099x; 1.3196x over previous
//
#include <hip/hip_runtime.h>
#include <math.h>

// ---------------- problem constants ----------------
constexpr int M1 = 2000, M2 = 400, BS = 8;
constexpr int AT = M1 + M2;            // 2400
constexpr int NN = BS * AT;            // 19200 nodes
constexpr int E1 = 60000, E2 = 20000, E3 = 20000;
constexpr int ET = E1 + E2 + E3;       // 100000
constexpr int H = 64, F = 64, NG = 50, L = 4, C = 4;
constexpr float CUTOFF = 10.0f;
constexpr float LOG2F_ = 0.6931471805599453f;

constexpr float SMEAR_STEP = 10.0f / 49.0f;
constexpr float SMEAR_COEFF = -12.005f;
constexpr float PI_OVER_CUT = 0.31415926535897932f; // pi/10

constexpr int NBLK = (ET + 255) / 256;  // 391 blocks in count/fill passes
constexpr int NBUCK = 12;               // (graph,color) buckets

// Edge-MLP interpolation table: W(d) tabulated at NT points over [0, CUTOFF]
// for each of the 48 (g,c,l) slices. |W''| ~ O(50) -> lerp err ~1.5e-4 abs.
constexpr int NT = 2048;
constexpr float DSCALE = (float)(NT - 1) / CUTOFF;

// ---------------- workspace layout (bytes) ----------------
constexpr size_t O_H     = 0;                         // h      [NN,64] f32
constexpr size_t O_DELTA = O_H     + (size_t)NN * 64 * 4;
constexpr size_t O_XG    = O_DELTA + (size_t)NN * 64 * 4;   // xg [3,NN,64]
constexpr size_t O_AGG   = O_XG    + (size_t)3 * NN * 64 * 4; // agg3 [3,NN,64]
constexpr size_t O_TAB   = O_AGG   + (size_t)3 * NN * 64 * 4; // tab [48,NT,64] (25.2MB <= old 25.6MB)
constexpr size_t O_INT   = O_TAB   + (size_t)ET * 64 * 4;
// int region (element offsets from O_INT):
constexpr int I_DEG   = 0;          // [3*AT]   (zeroed)
constexpr int I_CUR   = 7200;       // [3*AT]   (zeroed)
constexpr int I_ZEND  = 14400;      // end of zeroed region
constexpr int I_BASE  = 14400;      // [3*(AT+1)] pad to 7204
constexpr int I_CBASE = 21604;      // [16] (unused now, kept)
constexpr int I_CSR   = 21620;      // [ET]
constexpr int I_CCSR  = 121620;     // [ET] (unused now, kept)
constexpr int I_LRANK = 221620;     // [ET]
constexpr int I_BCNT  = 321620;     // [NBLK*12]
constexpr int I_BBASE = 326312;     // [NBLK*12]

__device__ inline float sspf(float x) {
    // shifted softplus: log(1+exp(x)) - log(2), numerically stable
    return fmaxf(x, 0.0f) + log1pf(expf(-fabsf(x))) - LOG2F_;
}

// fast variant for the edge MLP (error ~1e-6 abs)
__device__ inline float sspf_fast(float x) {
    float t = __expf(-fabsf(x));
    return fmaxf(x, 0.0f) + __logf(1.0f + t) - LOG2F_;
}

__device__ inline int graph_off(int g) { return g == 0 ? 0 : (g == 1 ? E1 : E1 + E2); }

__device__ inline void edge_decode(int idx, int& g, int& e,
                                   const int* ei1, const int* ei2, const int* ei3,
                                   const int* c1, const int* c2, const int* c3,
                                   const int*& ei, const int*& cl) {
    if (idx < E1)            { g = 0; e = idx;           ei = ei1; cl = c1; }
    else if (idx < E1 + E2)  { g = 1; e = idx - E1;      ei = ei2; cl = c2; }
    else                     { g = 2; e = idx - E1 - E2; ei = ei3; cl = c3; }
}

// ---------------- setup kernels ----------------
__global__ void k_init_h(const int* __restrict__ sites, const int* __restrict__ sites_p,
                         const float* __restrict__ emb_w, const float* __restrict__ emb_p_w,
                         float* __restrict__ h) {
    int idx = blockIdx.x * blockDim.x + threadIdx.x;
    if (idx >= NN * 64) return;
    int f = idx & 63;
    int n = idx >> 6;
    int b = n / AT;
    int i = n - b * AT;
    float v;
    if (i < M1) v = emb_w[sites[b * M1 + i] * H + f];
    else        v = emb_p_w[sites_p[b * M2 + (i - M1)] * H + f];
    h[idx] = v;
}

// dst-degree histogram (7200 spread addresses, low contention)
__global__ void k_count(const int* __restrict__ ei1, const int* __restrict__ ei2,
                        const int* __restrict__ ei3, const int* __restrict__ c1,
                        const int* __restrict__ c2, const int* __restrict__ c3,
                        int* __restrict__ deg, int* __restrict__ bcnt,
                        int* __restrict__ lrank) {
    int t = threadIdx.x;
    int idx = blockIdx.x * blockDim.x + t;
    if (idx < ET) {
        int g, e; const int* ei; const int* cl;
        edge_decode(idx, g, e, ei1, ei2, ei3, c1, c2, c3, ei, cl);
        atomicAdd(&deg[g * AT + ei[2 * e + 1]], 1);
    }
    (void)bcnt; (void)lrank;
}

// Blocks 0..2: exclusive scan of deg[g] -> base[g].
__global__ void k_scan(const int* __restrict__ deg, int* __restrict__ base,
                       const int* __restrict__ bcnt, int* __restrict__ bbase,
                       int* __restrict__ cbase) {
    const int T = 256, CH = 10; // 2560 >= 2400
    int t = threadIdx.x;
    __shared__ int lsum[T];
    int g = blockIdx.x;
    int loc[CH];
    int s = 0;
    #pragma unroll
    for (int i = 0; i < CH; i++) {
        int idx = t * CH + i;
        int v = (idx < AT) ? deg[g * AT + idx] : 0;
        loc[i] = s;
        s += v;
    }
    lsum[t] = s;
    __syncthreads();
    for (int off = 1; off < T; off <<= 1) {
        int v = 0;
        if (t >= off) v = lsum[t - off];
        __syncthreads();
        lsum[t] += v;
        __syncthreads();
    }
    int tb = lsum[t] - s; // exclusive prefix for this thread
    #pragma unroll
    for (int i = 0; i < CH; i++) {
        int idx = t * CH + i;
        if (idx < AT) base[g * (AT + 1) + idx] = tb + loc[i];
    }
    if (t == T - 1) base[g * (AT + 1) + AT] = lsum[T - 1];
    (void)bcnt; (void)bbase; (void)cbase;
}

// fill dst-CSR (cur atomics, spread addresses)
__global__ void k_fill(const int* __restrict__ ei1, const int* __restrict__ ei2,
                       const int* __restrict__ ei3, const int* __restrict__ c1,
                       const int* __restrict__ c2, const int* __restrict__ c3,
                       const int* __restrict__ base, int* __restrict__ cur,
                       int* __restrict__ csr) {
    int idx = blockIdx.x * blockDim.x + threadIdx.x;
    if (idx >= ET) return;
    int g, e; const int* ei; const int* cl;
    edge_decode(idx, g, e, ei1, ei2, ei3, c1, c2, c3, ei, cl);
    int dst = ei[2 * e + 1];
    int p = base[g * (AT + 1) + dst] + atomicAdd(&cur[g * AT + dst], 1);
    csr[graph_off(g) + p] = e;
}

// ---------------- edge-MLP table build ----------------
// One lane per d-sample: full 50->64->64 MLP with wave-uniform (SGPR) weights.
// Slice s = (g*C + c)*L + l; tab[s][p][0..63] = W(d_p) * Ccut(d_p).
constexpr int TBLK = NT / 256;       // blocks per slice (8)
__global__ __launch_bounds__(256) void k_table(
    const float* __restrict__ mlp_w1, const float* __restrict__ mlp_b1,
    const float* __restrict__ mlp_w2, const float* __restrict__ mlp_b2,
    float* __restrict__ tab) {
    int s = blockIdx.x / TBLK;
    int p = (blockIdx.x % TBLK) * 256 + threadIdx.x;
    int l = s % L;
    int gc = s / L;
    int c = gc % C;
    int g = gc / C;
    float d = (float)p * (CUTOFF / (float)(NT - 1));

    size_t wb = (size_t)((l * 3 + g) * C + c);
    const float* w1 = mlp_w1 + wb * NG * F;
    const float* w2 = mlp_w2 + wb * F * F;
    const float* b1 = mlp_b1 + wb * F;
    const float* b2 = mlp_b2 + wb * F;

    float attr[NG];
    #pragma unroll
    for (int k = 0; k < NG; k++) {
        float dd = d - (float)k * SMEAR_STEP;
        attr[k] = __expf(SMEAR_COEFF * dd * dd);
    }

    float hmid[F];
    #pragma unroll
    for (int jt = 0; jt < F; jt += 16) {
        float acc[16];
        #pragma unroll
        for (int u = 0; u < 16; u++) acc[u] = b1[jt + u];
        #pragma unroll
        for (int k = 0; k < NG; k++) {
            float a = attr[k];
            #pragma unroll
            for (int u = 0; u < 16; u++)
                acc[u] = fmaf(a, w1[k * F + jt + u], acc[u]);
        }
        #pragma unroll
        for (int u = 0; u < 16; u++) hmid[jt + u] = sspf_fast(acc[u]);
    }

    float ccut = 0.5f * (__cosf(d * PI_OVER_CUT) + 1.0f);
    float* orow = tab + ((size_t)s * NT + p) * 64;

    #pragma unroll
    for (int ft = 0; ft < F; ft += 16) {
        float acc[16];
        #pragma unroll
        for (int u = 0; u < 16; u++) acc[u] = b2[ft + u];
        #pragma unroll
        for (int j = 0; j < F; j++) {
            float hv = hmid[j];
            #pragma unroll
            for (int u = 0; u < 16; u++)
                acc[u] = fmaf(hv, w2[j * F + ft + u], acc[u]);
        }
        #pragma unroll
        for (int u = 0; u < 16; u += 4) {
            float4 v = make_float4(acc[u] * ccut, acc[u + 1] * ccut,
                                   acc[u + 2] * ccut, acc[u + 3] * ccut);
            *reinterpret_cast<float4*>(orow + ft + u) = v;
        }
    }
}

// ---------------- per-layer kernels ----------------
// x_g = h @ conv_w1[l,g]  (no bias), for all 3 graphs; 2-row interleave for ILP
constexpr int X_ROWS = 16;
constexpr int X_WPG = NN / X_ROWS;  // 1200 waves per graph
__global__ __launch_bounds__(256) void k_lin1(
    const float* __restrict__ h, const float* __restrict__ conv_w1,
    float* __restrict__ xg, int l) {
    const int lane = threadIdx.x & 63;
    int w = blockIdx.x * 4 + (threadIdx.x >> 6);
    int g = w / X_WPG;
    int rw = w - g * X_WPG;
    const float* wm = conv_w1 + (size_t)(l * 3 + g) * H * F;
    float wc[H];
    #pragma unroll
    for (int k = 0; k < H; k++) wc[k] = wm[k * F + lane];
    float* xo = xg + (size_t)g * NN * F;
    int r0 = rw * X_ROWS;
    for (int r = r0; r < r0 + X_ROWS; r += 2) {
        float hv0 = h[(size_t)r * H + lane];
        float hv1 = h[(size_t)(r + 1) * H + lane];
        float a0 = 0.0f, a1 = 0.0f;
        #pragma unroll
        for (int k = 0; k < H; k++) {
            a0 = fmaf(__shfl(hv0, k), wc[k], a0);
            a1 = fmaf(__shfl(hv1, k), wc[k], a1);
        }
        xo[(size_t)r * F + lane] = a0;
        xo[(size_t)(r + 1) * F + lane] = a1;
    }
}

// Aggregation with in-place W interpolation: one wave per (g,dst), all 8
// batches in registers; 2-edge unroll to pipeline the indirection chain.
__global__ __launch_bounds__(256) void k_agg(
    const int* __restrict__ csr, const int* __restrict__ base,
    const int* __restrict__ ei1, const int* __restrict__ ei2,
    const int* __restrict__ ei3,
    const int* __restrict__ c1, const int* __restrict__ c2,
    const int* __restrict__ c3,
    const float* __restrict__ ew1, const float* __restrict__ ew2,
    const float* __restrict__ ew3,
    const float* __restrict__ xg, const float* __restrict__ tab,
    float* __restrict__ agg3, int l) {
    const int lane = threadIdx.x & 63;
    int w = blockIdx.x * 4 + (threadIdx.x >> 6); // 0..7199
    int g = w / AT;
    int dst = w - g * AT;
    const int* ei; const int* cl; const float* ew;
    if (g == 0)      { ei = ei1; cl = c1; ew = ew1; }
    else if (g == 1) { ei = ei2; cl = c2; ew = ew2; }
    else             { ei = ei3; cl = c3; ew = ew3; }
    int goff = graph_off(g);
    int s = base[g * (AT + 1) + dst];
    int e = base[g * (AT + 1) + dst + 1];
    const float* tg = tab + (size_t)(g * C) * L * NT * 64;
    float acc[BS];
    #pragma unroll
    for (int b = 0; b < BS; b++) acc[b] = 0.0f;
    int i = s;
    for (; i + 2 <= e; i += 2) {
        int eidA = csr[goff + i], eidB = csr[goff + i + 1];
        int srcA = ei[2 * eidA], srcB = ei[2 * eidB];
        int cA = cl[eidA], cB = cl[eidB];
        float dA = ew[eidA], dB = ew[eidB];
        float tA = dA * DSCALE, tB = dB * DSCALE;
        int iA = min((int)tA, NT - 2), iB = min((int)tB, NT - 2);
        float frA = tA - (float)iA, frB = tB - (float)iB;
        const float* rA = tg + ((size_t)(cA * L + l) * NT + iA) * 64;
        const float* rB = tg + ((size_t)(cB * L + l) * NT + iB) * 64;
        float rA0 = rA[lane], rA1 = rA[64 + lane];
        float rB0 = rB[lane], rB1 = rB[64 + lane];
        float wvA = fmaf(frA, rA1 - rA0, rA0);
        float wvB = fmaf(frB, rB1 - rB0, rB0);
        const float* xbA = xg + ((size_t)g * NN + srcA) * F + lane;
        const float* xbB = xg + ((size_t)g * NN + srcB) * F + lane;
        #pragma unroll
        for (int b = 0; b < BS; b++) {
            acc[b] = fmaf(xbA[(size_t)b * AT * F], wvA, acc[b]);
            acc[b] = fmaf(xbB[(size_t)b * AT * F], wvB, acc[b]);
        }
    }
    if (i < e) {
        int eid = csr[goff + i];
        int src = ei[2 * eid];
        int c = cl[eid];
        float d = ew[eid];
        float t = d * DSCALE;
        int i0 = min((int)t, NT - 2);
        float fr = t - (float)i0;
        const float* r = tg + ((size_t)(c * L + l) * NT + i0) * 64;
        float r0 = r[lane], r1 = r[64 + lane];
        float wv = fmaf(fr, r1 - r0, r0);
        const float* xb = xg + ((size_t)g * NN + src) * F + lane;
        #pragma unroll
        for (int b = 0; b < BS; b++)
            acc[b] = fmaf(xb[(size_t)b * AT * F], wv, acc[b]);
    }
    float* ao = agg3 + ((size_t)g * NN + dst) * F + lane;
    #pragma unroll
    for (int b = 0; b < BS; b++) ao[(size_t)b * AT * F] = acc[b];
}

// lin2 + ssp + block-linear, accumulate delta; g==2 folds h += delta.
// 2-row interleave to break the serial shfl+FMA chains.
constexpr int N2_ROWS = 8;
__global__ __launch_bounds__(256) void k_node2(
    const float* __restrict__ agg3, const float* __restrict__ conv_w2,
    const float* __restrict__ conv_b2, const float* __restrict__ blk_w,
    const float* __restrict__ blk_b, float* __restrict__ delta,
    float* __restrict__ h, int l, int g) {
    const int lane = threadIdx.x & 63;
    int w = blockIdx.x * 4 + (threadIdx.x >> 6);
    size_t pb = (size_t)(l * 3 + g);
    const float* cw2 = conv_w2 + pb * F * H;
    const float* bw = blk_w + pb * H * H;
    float c2c[F], bwc[H];
    #pragma unroll
    for (int k = 0; k < F; k++) c2c[k] = cw2[k * H + lane];
    #pragma unroll
    for (int k = 0; k < H; k++) bwc[k] = bw[k * H + lane];
    float cb2c = conv_b2[pb * H + lane];
    float bbc = blk_b[pb * H + lane];
    const float* ag = agg3 + (size_t)g * NN * F;
    int r0 = w * N2_ROWS;
    for (int r = r0; r < r0 + N2_ROWS; r += 2) {
        float av0 = ag[(size_t)r * F + lane];
        float av1 = ag[(size_t)(r + 1) * F + lane];
        float a0 = cb2c, a1 = cb2c;
        #pragma unroll
        for (int k = 0; k < F; k++) {
            a0 = fmaf(__shfl(av0, k), c2c[k], a0);
            a1 = fmaf(__shfl(av1, k), c2c[k], a1);
        }
        float t0 = sspf(a0), t1 = sspf(a1);
        float o0 = bbc, o1 = bbc;
        #pragma unroll
        for (int j = 0; j < H; j++) {
            o0 = fmaf(__shfl(t0, j), bwc[j], o0);
            o1 = fmaf(__shfl(t1, j), bwc[j], o1);
        }
        size_t ix0 = (size_t)r * H + lane;
        size_t ix1 = (size_t)(r + 1) * H + lane;
        if (g == 0)      { delta[ix0] = o0; delta[ix1] = o1; }
        else if (g == 1) { delta[ix0] += o0; delta[ix1] += o1; }
        else             { h[ix0] += delta[ix0] + o0; h[ix1] += delta[ix1] + o1; }
    }
}

// Readout: o[b] = sum_pore h . weff + M2*(b1.W2 + b2), weff = W1@W2
__global__ void k_read(const float* __restrict__ h,
                       const float* __restrict__ w1, const float* __restrict__ b1,
                       const float* __restrict__ w2, const float* __restrict__ b2,
                       float* __restrict__ out) {
    int b = blockIdx.x;
    int lane = threadIdx.x & 63;
    int wv = threadIdx.x >> 6;
    __shared__ float part[4];
    float weff = 0.0f;
    #pragma unroll
    for (int j = 0; j < H / 2; j++) weff = fmaf(w1[lane * (H / 2) + j], w2[j], weff);
    float acc = 0.0f;
    for (int i = wv * (M2 / 4); i < (wv + 1) * (M2 / 4); i++)
        acc += h[((size_t)b * AT + M1 + i) * H + lane];
    float v = acc * weff;
    for (int off = 32; off; off >>= 1) v += __shfl_xor(v, off);
    if (lane == 0) part[wv] = v;
    __syncthreads();
    if (threadIdx.x == 0) {
        float bias = b2[0];
        for (int j = 0; j < H / 2; j++) bias = fmaf(b1[j], w2[j], bias);
        out[b] = part[0] + part[1] + part[2] + part[3] + (float)M2 * bias;
    }
}

// ---------------- launcher ----------------
extern "C" void kernel_launch(void* const* d_in, const int* in_sizes, int n_in,
                              void* d_out, int out_size, void* d_ws, size_t ws_size,
                              hipStream_t stream) {
    const int* sites   = (const int*)d_in[0];
    const int* sites_p = (const int*)d_in[1];
    const int* ei1 = (const int*)d_in[2];
    const float* ew1 = (const float*)d_in[3];
    const int* c1 = (const int*)d_in[4];
    const int* ei2 = (const int*)d_in[5];
    const float* ew2 = (const float*)d_in[6];
    const int* c2 = (const int*)d_in[7];
    const int* ei3 = (const int*)d_in[8];
    const float* ew3 = (const float*)d_in[9];
    const int* c3 = (const int*)d_in[10];
    const float* emb_w   = (const float*)d_in[11];
    const float* emb_p_w = (const float*)d_in[12];
    const float* mlp_w1 = (const float*)d_in[13];
    const float* mlp_b1 = (const float*)d_in[14];
    const float* mlp_w2 = (const float*)d_in[15];
    const float* mlp_b2 = (const float*)d_in[16];
    const float* conv_w1 = (const float*)d_in[17];
    const float* conv_w2 = (const float*)d_in[18];
    const float* conv_b2 = (const float*)d_in[19];
    const float* blk_w = (const float*)d_in[20];
    const float* blk_b = (const float*)d_in[21];
    const float* out_w1 = (const float*)d_in[22];
    const float* out_b1 = (const float*)d_in[23];
    const float* out_w2 = (const float*)d_in[24];
    const float* out_b2 = (const float*)d_in[25];

    char* ws = (char*)d_ws;
    float* h     = (float*)(ws + O_H);
    float* delta = (float*)(ws + O_DELTA);
    float* xg    = (float*)(ws + O_XG);
    float* agg3  = (float*)(ws + O_AGG);
    float* tab   = (float*)(ws + O_TAB);
    int* ip    = (int*)(ws + O_INT);
    int* deg   = ip + I_DEG;
    int* cur   = ip + I_CUR;
    int* ibase = ip + I_BASE;
    int* csr   = ip + I_CSR;

    // zero the counters (ws is re-poisoned to 0xAA before every launch)
    hipMemsetAsync(ip, 0, (size_t)I_ZEND * sizeof(int), stream);

    k_table<<<48 * TBLK, 256, 0, stream>>>(mlp_w1, mlp_b1, mlp_w2, mlp_b2, tab);
    k_init_h<<<(NN * 64 + 255) / 256, 256, 0, stream>>>(sites, sites_p, emb_w, emb_p_w, h);
    k_count<<<NBLK, 256, 0, stream>>>(ei1, ei2, ei3, c1, c2, c3, deg, nullptr, nullptr);
    k_scan<<<3, 256, 0, stream>>>(deg, ibase, nullptr, nullptr, nullptr);
    k_fill<<<NBLK, 256, 0, stream>>>(ei1, ei2, ei3, c1, c2, c3, ibase, cur, csr);

    for (int l = 0; l < L; l++) {
        k_lin1<<<3 * X_WPG / 4, 256, 0, stream>>>(h, conv_w1, xg, l);
        k_agg<<<3 * AT / 4, 256, 0, stream>>>(csr, ibase, ei1, ei2, ei3,
                                              c1, c2, c3, ew1, ew2, ew3,
                                              xg, tab, agg3, l);
        for (int g = 0; g < 3; g++) {
            k_node2<<<NN / N2_ROWS / 4, 256, 0, stream>>>(agg3, conv_w2, conv_b2,
                                                          blk_w, blk_b, delta, h, l, g);
        }
    }
    k_read<<<BS, 256, 0, stream>>>(h, out_w1, out_b1, out_w2, out_b2, (float*)d_out);
}

// Round 6
// 998.240 us; speedup vs baseline: 3.2170x; 1.1449x over previous
//
#include <hip/hip_runtime.h>
#include <math.h>

// ---------------- problem constants ----------------
constexpr int M1 = 2000, M2 = 400, BS = 8;
constexpr int AT = M1 + M2;            // 2400
constexpr int NN = BS * AT;            // 19200 nodes
constexpr int E1 = 60000, E2 = 20000, E3 = 20000;
constexpr int ET = E1 + E2 + E3;       // 100000
constexpr int H = 64, F = 64, NG = 50, L = 4, C = 4;
constexpr float CUTOFF = 10.0f;
constexpr float LOG2F_ = 0.6931471805599453f;

constexpr float SMEAR_STEP = 10.0f / 49.0f;
constexpr float SMEAR_COEFF = -12.005f;
constexpr float PI_OVER_CUT = 0.31415926535897932f; // pi/10

constexpr int NBLK = (ET + 255) / 256;  // 391 blocks in count/fill passes

// Edge-MLP lerp table: NT points over [0,CUTOFF] per (g,c,l) slice (48 slices).
// |W''|~5 -> lerp err ~ (10/511)^2/8*5 ~ 2.4e-4 abs. Table 6.3MB (L2-resident).
constexpr int NT = 512;
constexpr float DSCALE = (float)(NT - 1) / CUTOFF;   // 51.1

// ---------------- workspace layout (bytes) ----------------
constexpr size_t O_H     = 0;                           // h   [NN,64] f32 (4.9MB)
constexpr size_t O_XG    = O_H   + (size_t)NN * 64 * 4; // xg  [3,NN,64] (14.7MB)
constexpr size_t O_AGG   = O_XG  + (size_t)3 * NN * 64 * 4; // agg3 [3,NN,64]
constexpr size_t O_TAB   = O_AGG + (size_t)3 * NN * 64 * 4; // tab [48,NT,64] (6.3MB)
constexpr size_t O_EDATA = O_TAB + (size_t)48 * NT * 64 * 4; // edata [ET] int4 (1.6MB)
constexpr size_t O_INT   = O_EDATA + (size_t)ET * 16;
// int region (element offsets from O_INT):
constexpr int I_DEG  = 0;      // [3*AT] zeroed
constexpr int I_CUR  = 7200;   // [3*AT] zeroed
constexpr int I_ZEND = 14400;
constexpr int I_BASE = 14400;  // [3*(AT+1)] = 7203, reserve 7216

__device__ inline float sspf(float x) {
    return fmaxf(x, 0.0f) + log1pf(expf(-fabsf(x))) - LOG2F_;
}
__device__ inline float sspf_fast(float x) {
    float t = __expf(-fabsf(x));
    return fmaxf(x, 0.0f) + __logf(1.0f + t) - LOG2F_;
}

__device__ inline int graph_off(int g) { return g == 0 ? 0 : (g == 1 ? E1 : E1 + E2); }

__device__ inline void edge_decode(int idx, int& g, int& e,
                                   const int* ei1, const int* ei2, const int* ei3,
                                   const int* c1, const int* c2, const int* c3,
                                   const int*& ei, const int*& cl) {
    if (idx < E1)            { g = 0; e = idx;           ei = ei1; cl = c1; }
    else if (idx < E1 + E2)  { g = 1; e = idx - E1;      ei = ei2; cl = c2; }
    else                     { g = 2; e = idx - E1 - E2; ei = ei3; cl = c3; }
}

// ---------------- setup kernels ----------------
__global__ void k_init_h(const int* __restrict__ sites, const int* __restrict__ sites_p,
                         const float* __restrict__ emb_w, const float* __restrict__ emb_p_w,
                         float* __restrict__ h) {
    int idx = blockIdx.x * blockDim.x + threadIdx.x;
    if (idx >= NN * 64) return;
    int f = idx & 63;
    int n = idx >> 6;
    int b = n / AT;
    int i = n - b * AT;
    float v;
    if (i < M1) v = emb_w[sites[b * M1 + i] * H + f];
    else        v = emb_p_w[sites_p[b * M2 + (i - M1)] * H + f];
    h[idx] = v;
}

// dst-degree histogram (7200 spread addresses, low contention)
__global__ void k_count(const int* __restrict__ ei1, const int* __restrict__ ei2,
                        const int* __restrict__ ei3, const int* __restrict__ c1,
                        const int* __restrict__ c2, const int* __restrict__ c3,
                        int* __restrict__ deg) {
    int idx = blockIdx.x * blockDim.x + threadIdx.x;
    if (idx >= ET) return;
    int g, e; const int* ei; const int* cl;
    edge_decode(idx, g, e, ei1, ei2, ei3, c1, c2, c3, ei, cl);
    atomicAdd(&deg[g * AT + ei[2 * e + 1]], 1);
}

// Blocks 0..2: exclusive scan of deg[g] -> base[g].
__global__ void k_scan(const int* __restrict__ deg, int* __restrict__ base) {
    const int T = 256, CH = 10; // 2560 >= 2400
    int t = threadIdx.x;
    __shared__ int lsum[T];
    int g = blockIdx.x;
    int loc[CH];
    int s = 0;
    #pragma unroll
    for (int i = 0; i < CH; i++) {
        int idx = t * CH + i;
        int v = (idx < AT) ? deg[g * AT + idx] : 0;
        loc[i] = s;
        s += v;
    }
    lsum[t] = s;
    __syncthreads();
    for (int off = 1; off < T; off <<= 1) {
        int v = 0;
        if (t >= off) v = lsum[t - off];
        __syncthreads();
        lsum[t] += v;
        __syncthreads();
    }
    int tb = lsum[t] - s;
    #pragma unroll
    for (int i = 0; i < CH; i++) {
        int idx = t * CH + i;
        if (idx < AT) base[g * (AT + 1) + idx] = tb + loc[i];
    }
    if (t == T - 1) base[g * (AT + 1) + AT] = lsum[T - 1];
}

// fill dst-CSR as packed edge records: {src, c*L*NT+i0, frac_bits, 0}
__global__ void k_fill(const int* __restrict__ ei1, const int* __restrict__ ei2,
                       const int* __restrict__ ei3, const int* __restrict__ c1,
                       const int* __restrict__ c2, const int* __restrict__ c3,
                       const float* __restrict__ ew1, const float* __restrict__ ew2,
                       const float* __restrict__ ew3,
                       const int* __restrict__ base, int* __restrict__ cur,
                       int4* __restrict__ edata) {
    int idx = blockIdx.x * blockDim.x + threadIdx.x;
    if (idx >= ET) return;
    int g, e; const int* ei; const int* cl;
    edge_decode(idx, g, e, ei1, ei2, ei3, c1, c2, c3, ei, cl);
    const float* ew = (g == 0) ? ew1 : (g == 1 ? ew2 : ew3);
    int dst = ei[2 * e + 1];
    int src = ei[2 * e];
    int p = base[g * (AT + 1) + dst] + atomicAdd(&cur[g * AT + dst], 1);
    float t = ew[e] * DSCALE;
    int i0 = min((int)t, NT - 2);
    float fr = t - (float)i0;
    int cb = cl[e] * (L * NT) + i0;
    edata[graph_off(g) + p] = make_int4(src, cb, __float_as_int(fr), 0);
}

// ---------------- edge-MLP table build ----------------
// One wave per (slice, point): lane = output feature, shfl broadcasts,
// weights as L1-cached vector loads. 24576 waves -> latency fully hidden.
__global__ __launch_bounds__(256) void k_table(
    const float* __restrict__ mlp_w1, const float* __restrict__ mlp_b1,
    const float* __restrict__ mlp_w2, const float* __restrict__ mlp_b2,
    float* __restrict__ tab) {
    const int lane = threadIdx.x & 63;
    int w = blockIdx.x * 4 + (threadIdx.x >> 6);
    int s = w >> 9;          // / NT(512) points per slice
    int p = w & (NT - 1);
    int l = s % L;
    int gc = s / L;
    int c = gc % C;
    int g = gc / C;
    float d = (float)p * (CUTOFF / (float)(NT - 1));

    size_t wb = (size_t)((l * 3 + g) * C + c);
    const float* w1 = mlp_w1 + wb * NG * F;
    const float* w2 = mlp_w2 + wb * F * F;
    float w1c[NG], w2c[F];
    #pragma unroll
    for (int k = 0; k < NG; k++) w1c[k] = w1[k * F + lane];
    #pragma unroll
    for (int k = 0; k < F; k++) w2c[k] = w2[k * F + lane];
    float b1c = mlp_b1[wb * F + lane];
    float b2c = mlp_b2[wb * F + lane];

    float dd = d - (float)lane * SMEAR_STEP;
    float av = (lane < NG) ? __expf(SMEAR_COEFF * dd * dd) : 0.0f;
    float acc = b1c;
    #pragma unroll
    for (int k = 0; k < NG; k++) acc = fmaf(__shfl(av, k), w1c[k], acc);
    float t = sspf_fast(acc);
    float acc2 = b2c;
    #pragma unroll
    for (int j = 0; j < F; j++) acc2 = fmaf(__shfl(t, j), w2c[j], acc2);
    float ccut = 0.5f * (__cosf(d * PI_OVER_CUT) + 1.0f);
    tab[((size_t)s * NT + p) * 64 + lane] = acc2 * ccut;
}

// ---------------- per-layer kernels ----------------
// x_g = h @ conv_w1[l,g]  (no bias), for all 3 graphs; 2-row interleave
constexpr int X_ROWS = 16;
constexpr int X_WPG = NN / X_ROWS;  // 1200 waves per graph
__global__ __launch_bounds__(256) void k_lin1(
    const float* __restrict__ h, const float* __restrict__ conv_w1,
    float* __restrict__ xg, int l) {
    const int lane = threadIdx.x & 63;
    int w = blockIdx.x * 4 + (threadIdx.x >> 6);
    int g = w / X_WPG;
    int rw = w - g * X_WPG;
    const float* wm = conv_w1 + (size_t)(l * 3 + g) * H * F;
    float wc[H];
    #pragma unroll
    for (int k = 0; k < H; k++) wc[k] = wm[k * F + lane];
    float* xo = xg + (size_t)g * NN * F;
    int r0 = rw * X_ROWS;
    for (int r = r0; r < r0 + X_ROWS; r += 2) {
        float hv0 = h[(size_t)r * H + lane];
        float hv1 = h[(size_t)(r + 1) * H + lane];
        float a0 = 0.0f, a1 = 0.0f;
        #pragma unroll
        for (int k = 0; k < H; k++) {
            a0 = fmaf(__shfl(hv0, k), wc[k], a0);
            a1 = fmaf(__shfl(hv1, k), wc[k], a1);
        }
        xo[(size_t)r * F + lane] = a0;
        xo[(size_t)(r + 1) * F + lane] = a1;
    }
}

// Aggregation: one wave per (g,dst); per edge one int4 record + table lerp;
// 8 batches in registers; 2-edge unroll pipelines the load chain.
__global__ __launch_bounds__(256) void k_agg(
    const int4* __restrict__ edata, const int* __restrict__ base,
    const float* __restrict__ xg, const float* __restrict__ tab,
    float* __restrict__ agg3, int l) {
    const int lane = threadIdx.x & 63;
    int w = blockIdx.x * 4 + (threadIdx.x >> 6); // 0..7199
    int g = w / AT;
    int dst = w - g * AT;
    const int4* ed = edata + graph_off(g);
    int s = base[g * (AT + 1) + dst];
    int e = base[g * (AT + 1) + dst + 1];
    const float* tg = tab + ((size_t)g * C * L * NT) * 64 + (size_t)l * NT * 64;
    const float* xgg = xg + (size_t)g * NN * F;
    float acc[BS];
    #pragma unroll
    for (int b = 0; b < BS; b++) acc[b] = 0.0f;
    int i = s;
    for (; i + 2 <= e; i += 2) {
        int4 mA = ed[i], mB = ed[i + 1];
        const float* rA = tg + (size_t)mA.y * 64;
        const float* rB = tg + (size_t)mB.y * 64;
        float frA = __int_as_float(mA.z), frB = __int_as_float(mB.z);
        float rA0 = rA[lane], rA1 = rA[64 + lane];
        float rB0 = rB[lane], rB1 = rB[64 + lane];
        float wvA = fmaf(frA, rA1 - rA0, rA0);
        float wvB = fmaf(frB, rB1 - rB0, rB0);
        const float* xbA = xgg + (size_t)mA.x * F + lane;
        const float* xbB = xgg + (size_t)mB.x * F + lane;
        #pragma unroll
        for (int b = 0; b < BS; b++) {
            acc[b] = fmaf(xbA[(size_t)b * AT * F], wvA, acc[b]);
            acc[b] = fmaf(xbB[(size_t)b * AT * F], wvB, acc[b]);
        }
    }
    if (i < e) {
        int4 m = ed[i];
        const float* r = tg + (size_t)m.y * 64;
        float fr = __int_as_float(m.z);
        float r0 = r[lane], r1 = r[64 + lane];
        float wv = fmaf(fr, r1 - r0, r0);
        const float* xb = xgg + (size_t)m.x * F + lane;
        #pragma unroll
        for (int b = 0; b < BS; b++)
            acc[b] = fmaf(xb[(size_t)b * AT * F], wv, acc[b]);
    }
    float* ao = agg3 + ((size_t)g * NN + dst) * F + lane;
    #pragma unroll
    for (int b = 0; b < BS; b++) ao[(size_t)b * AT * F] = acc[b];
}

// Fused: for each row, sum over the 3 graphs of (lin2 -> ssp -> block linear),
// then h += sum. delta array eliminated; one dispatch per layer.
constexpr int N2_ROWS = 8;
__global__ __launch_bounds__(256) void k_node2(
    const float* __restrict__ agg3, const float* __restrict__ conv_w2,
    const float* __restrict__ conv_b2, const float* __restrict__ blk_w,
    const float* __restrict__ blk_b, float* __restrict__ h, int l) {
    const int lane = threadIdx.x & 63;
    int w = blockIdx.x * 4 + (threadIdx.x >> 6);
    int r0 = w * N2_ROWS;
    float osum[N2_ROWS];
    #pragma unroll
    for (int u = 0; u < N2_ROWS; u++) osum[u] = 0.0f;
    #pragma unroll 1   // keep ONE weight set live at a time (register pressure)
    for (int g = 0; g < 3; g++) {
        size_t pb = (size_t)(l * 3 + g);
        const float* cw2 = conv_w2 + pb * F * H;
        const float* bw = blk_w + pb * H * H;
        float c2c[F], bwc[H];
        #pragma unroll
        for (int k = 0; k < F; k++) c2c[k] = cw2[k * H + lane];
        #pragma unroll
        for (int k = 0; k < H; k++) bwc[k] = bw[k * H + lane];
        float cb2c = conv_b2[pb * H + lane];
        float bbc = blk_b[pb * H + lane];
        const float* ag = agg3 + (size_t)g * NN * F;
        #pragma unroll
        for (int u = 0; u < N2_ROWS; u += 2) {
            int r = r0 + u;
            float av0 = ag[(size_t)r * F + lane];
            float av1 = ag[(size_t)(r + 1) * F + lane];
            float a0 = cb2c, a1 = cb2c;
            #pragma unroll
            for (int k = 0; k < F; k++) {
                a0 = fmaf(__shfl(av0, k), c2c[k], a0);
                a1 = fmaf(__shfl(av1, k), c2c[k], a1);
            }
            float t0 = sspf(a0), t1 = sspf(a1);
            float o0 = bbc, o1 = bbc;
            #pragma unroll
            for (int j = 0; j < H; j++) {
                o0 = fmaf(__shfl(t0, j), bwc[j], o0);
                o1 = fmaf(__shfl(t1, j), bwc[j], o1);
            }
            osum[u] += o0;
            osum[u + 1] += o1;
        }
    }
    #pragma unroll
    for (int u = 0; u < N2_ROWS; u++) {
        size_t ix = (size_t)(r0 + u) * H + lane;
        h[ix] += osum[u];
    }
}

// Readout: o[b] = sum_pore h . weff + M2*(b1.W2 + b2), weff = W1@W2
__global__ void k_read(const float* __restrict__ h,
                       const float* __restrict__ w1, const float* __restrict__ b1,
                       const float* __restrict__ w2, const float* __restrict__ b2,
                       float* __restrict__ out) {
    int b = blockIdx.x;
    int lane = threadIdx.x & 63;
    int wv = threadIdx.x >> 6;
    __shared__ float part[4];
    float weff = 0.0f;
    #pragma unroll
    for (int j = 0; j < H / 2; j++) weff = fmaf(w1[lane * (H / 2) + j], w2[j], weff);
    float acc = 0.0f;
    for (int i = wv * (M2 / 4); i < (wv + 1) * (M2 / 4); i++)
        acc += h[((size_t)b * AT + M1 + i) * H + lane];
    float v = acc * weff;
    for (int off = 32; off; off >>= 1) v += __shfl_xor(v, off);
    if (lane == 0) part[wv] = v;
    __syncthreads();
    if (threadIdx.x == 0) {
        float bias = b2[0];
        for (int j = 0; j < H / 2; j++) bias = fmaf(b1[j], w2[j], bias);
        out[b] = part[0] + part[1] + part[2] + part[3] + (float)M2 * bias;
    }
}

// ---------------- launcher ----------------
extern "C" void kernel_launch(void* const* d_in, const int* in_sizes, int n_in,
                              void* d_out, int out_size, void* d_ws, size_t ws_size,
                              hipStream_t stream) {
    const int* sites   = (const int*)d_in[0];
    const int* sites_p = (const int*)d_in[1];
    const int* ei1 = (const int*)d_in[2];
    const float* ew1 = (const float*)d_in[3];
    const int* c1 = (const int*)d_in[4];
    const int* ei2 = (const int*)d_in[5];
    const float* ew2 = (const float*)d_in[6];
    const int* c2 = (const int*)d_in[7];
    const int* ei3 = (const int*)d_in[8];
    const float* ew3 = (const float*)d_in[9];
    const int* c3 = (const int*)d_in[10];
    const float* emb_w   = (const float*)d_in[11];
    const float* emb_p_w = (const float*)d_in[12];
    const float* mlp_w1 = (const float*)d_in[13];
    const float* mlp_b1 = (const float*)d_in[14];
    const float* mlp_w2 = (const float*)d_in[15];
    const float* mlp_b2 = (const float*)d_in[16];
    const float* conv_w1 = (const float*)d_in[17];
    const float* conv_w2 = (const float*)d_in[18];
    const float* conv_b2 = (const float*)d_in[19];
    const float* blk_w = (const float*)d_in[20];
    const float* blk_b = (const float*)d_in[21];
    const float* out_w1 = (const float*)d_in[22];
    const float* out_b1 = (const float*)d_in[23];
    const float* out_w2 = (const float*)d_in[24];
    const float* out_b2 = (const float*)d_in[25];

    char* ws = (char*)d_ws;
    float* h    = (float*)(ws + O_H);
    float* xg   = (float*)(ws + O_XG);
    float* agg3 = (float*)(ws + O_AGG);
    float* tab  = (float*)(ws + O_TAB);
    int4*  edata = (int4*)(ws + O_EDATA);
    int* ip    = (int*)(ws + O_INT);
    int* deg   = ip + I_DEG;
    int* cur   = ip + I_CUR;
    int* ibase = ip + I_BASE;

    // zero the counters (ws is re-poisoned to 0xAA before every launch)
    hipMemsetAsync(ip, 0, (size_t)I_ZEND * sizeof(int), stream);

    // one WAVE per (slice,point): 48*NT waves = 48*NT/4 blocks of 256 threads
    k_table<<<48 * NT / 4, 256, 0, stream>>>(mlp_w1, mlp_b1, mlp_w2, mlp_b2, tab);
    k_init_h<<<(NN * 64 + 255) / 256, 256, 0, stream>>>(sites, sites_p, emb_w, emb_p_w, h);
    k_count<<<NBLK, 256, 0, stream>>>(ei1, ei2, ei3, c1, c2, c3, deg);
    k_scan<<<3, 256, 0, stream>>>(deg, ibase);
    k_fill<<<NBLK, 256, 0, stream>>>(ei1, ei2, ei3, c1, c2, c3, ew1, ew2, ew3,
                                     ibase, cur, edata);

    for (int l = 0; l < L; l++) {
        k_lin1<<<3 * X_WPG / 4, 256, 0, stream>>>(h, conv_w1, xg, l);
        k_agg<<<3 * AT / 4, 256, 0, stream>>>(edata, ibase, xg, tab, agg3, l);
        k_node2<<<NN / N2_ROWS / 4, 256, 0, stream>>>(agg3, conv_w2, conv_b2,
                                                      blk_w, blk_b, h, l);
    }
    k_read<<<BS, 256, 0, stream>>>(h, out_w1, out_b1, out_w2, out_b2, (float*)d_out);
}

// Round 7
// 511.418 us; speedup vs baseline: 6.2793x; 1.9519x over previous
//
#include <hip/hip_runtime.h>
#include <math.h>

// ---------------- problem constants ----------------
constexpr int M1 = 2000, M2 = 400, BS = 8;
constexpr int AT = M1 + M2;            // 2400
constexpr int NN = BS * AT;            // 19200 nodes
constexpr int E1 = 60000, E2 = 20000, E3 = 20000;
constexpr int ET = E1 + E2 + E3;       // 100000
constexpr int H = 64, F = 64, NG = 50, L = 4, C = 4;
constexpr float CUTOFF = 10.0f;
constexpr float LOG2F_ = 0.6931471805599453f;

constexpr float SMEAR_STEP = 10.0f / 49.0f;
constexpr float SMEAR_COEFF = -12.005f;
constexpr float PI_OVER_CUT = 0.31415926535897932f; // pi/10

constexpr int NBLK = (ET + 255) / 256;  // 391 blocks in count/fill passes

// Edge-MLP lerp table: NT points over [0,CUTOFF] per (g,c,l) slice (48 slices).
constexpr int NT = 512;
constexpr float DSCALE = (float)(NT - 1) / CUTOFF;   // 51.1

// GEMM tiling
constexpr int TILE_M = 32;
constexpr int MT = NN / TILE_M;        // 600 row-tiles

// ---------------- workspace layout (bytes) ----------------
constexpr size_t O_H     = 0;                           // h   [NN,64] f32 (4.9MB)
constexpr size_t O_XG    = O_H   + (size_t)NN * 64 * 4; // xg  [3,NN,64] (also reused as tmp)
constexpr size_t O_AGG   = O_XG  + (size_t)3 * NN * 64 * 4; // agg3 [3,NN,64]
constexpr size_t O_TAB   = O_AGG + (size_t)3 * NN * 64 * 4; // tab [48,NT,64] (6.3MB)
constexpr size_t O_EDATA = O_TAB + (size_t)48 * NT * 64 * 4; // edata [ET] int4 (1.6MB)
constexpr size_t O_INT   = O_EDATA + (size_t)ET * 16;
// int region (element offsets from O_INT):
constexpr int I_DEG  = 0;      // [3*AT] zeroed
constexpr int I_CUR  = 7200;   // [3*AT] zeroed
constexpr int I_ZEND = 14400;
constexpr int I_BASE = 14400;  // [3*(AT+1)] = 7203, reserve 7216

__device__ inline float sspf(float x) {
    return fmaxf(x, 0.0f) + log1pf(expf(-fabsf(x))) - LOG2F_;
}
__device__ inline float sspf_fast(float x) {
    float t = __expf(-fabsf(x));
    return fmaxf(x, 0.0f) + __logf(1.0f + t) - LOG2F_;
}

__device__ inline int graph_off(int g) { return g == 0 ? 0 : (g == 1 ? E1 : E1 + E2); }

__device__ inline void edge_decode(int idx, int& g, int& e,
                                   const int* ei1, const int* ei2, const int* ei3,
                                   const int* c1, const int* c2, const int* c3,
                                   const int*& ei, const int*& cl) {
    if (idx < E1)            { g = 0; e = idx;           ei = ei1; cl = c1; }
    else if (idx < E1 + E2)  { g = 1; e = idx - E1;      ei = ei2; cl = c2; }
    else                     { g = 2; e = idx - E1 - E2; ei = ei3; cl = c3; }
}

// ---------------- setup kernels ----------------
__global__ void k_init_h(const int* __restrict__ sites, const int* __restrict__ sites_p,
                         const float* __restrict__ emb_w, const float* __restrict__ emb_p_w,
                         float* __restrict__ h) {
    int idx = blockIdx.x * blockDim.x + threadIdx.x;
    if (idx >= NN * 64) return;
    int f = idx & 63;
    int n = idx >> 6;
    int b = n / AT;
    int i = n - b * AT;
    float v;
    if (i < M1) v = emb_w[sites[b * M1 + i] * H + f];
    else        v = emb_p_w[sites_p[b * M2 + (i - M1)] * H + f];
    h[idx] = v;
}

__global__ void k_count(const int* __restrict__ ei1, const int* __restrict__ ei2,
                        const int* __restrict__ ei3, const int* __restrict__ c1,
                        const int* __restrict__ c2, const int* __restrict__ c3,
                        int* __restrict__ deg) {
    int idx = blockIdx.x * blockDim.x + threadIdx.x;
    if (idx >= ET) return;
    int g, e; const int* ei; const int* cl;
    edge_decode(idx, g, e, ei1, ei2, ei3, c1, c2, c3, ei, cl);
    atomicAdd(&deg[g * AT + ei[2 * e + 1]], 1);
}

__global__ void k_scan(const int* __restrict__ deg, int* __restrict__ base) {
    const int T = 256, CH = 10; // 2560 >= 2400
    int t = threadIdx.x;
    __shared__ int lsum[T];
    int g = blockIdx.x;
    int loc[CH];
    int s = 0;
    #pragma unroll
    for (int i = 0; i < CH; i++) {
        int idx = t * CH + i;
        int v = (idx < AT) ? deg[g * AT + idx] : 0;
        loc[i] = s;
        s += v;
    }
    lsum[t] = s;
    __syncthreads();
    for (int off = 1; off < T; off <<= 1) {
        int v = 0;
        if (t >= off) v = lsum[t - off];
        __syncthreads();
        lsum[t] += v;
        __syncthreads();
    }
    int tb = lsum[t] - s;
    #pragma unroll
    for (int i = 0; i < CH; i++) {
        int idx = t * CH + i;
        if (idx < AT) base[g * (AT + 1) + idx] = tb + loc[i];
    }
    if (t == T - 1) base[g * (AT + 1) + AT] = lsum[T - 1];
}

__global__ void k_fill(const int* __restrict__ ei1, const int* __restrict__ ei2,
                       const int* __restrict__ ei3, const int* __restrict__ c1,
                       const int* __restrict__ c2, const int* __restrict__ c3,
                       const float* __restrict__ ew1, const float* __restrict__ ew2,
                       const float* __restrict__ ew3,
                       const int* __restrict__ base, int* __restrict__ cur,
                       int4* __restrict__ edata) {
    int idx = blockIdx.x * blockDim.x + threadIdx.x;
    if (idx >= ET) return;
    int g, e; const int* ei; const int* cl;
    edge_decode(idx, g, e, ei1, ei2, ei3, c1, c2, c3, ei, cl);
    const float* ew = (g == 0) ? ew1 : (g == 1 ? ew2 : ew3);
    int dst = ei[2 * e + 1];
    int src = ei[2 * e];
    int p = base[g * (AT + 1) + dst] + atomicAdd(&cur[g * AT + dst], 1);
    float t = ew[e] * DSCALE;
    int i0 = min((int)t, NT - 2);
    float fr = t - (float)i0;
    int cb = cl[e] * (L * NT) + i0;
    edata[graph_off(g) + p] = make_int4(src, cb, __float_as_int(fr), 0);
}

// ---------------- edge-MLP table build ----------------
__global__ __launch_bounds__(256) void k_table(
    const float* __restrict__ mlp_w1, const float* __restrict__ mlp_b1,
    const float* __restrict__ mlp_w2, const float* __restrict__ mlp_b2,
    float* __restrict__ tab) {
    const int lane = threadIdx.x & 63;
    int w = blockIdx.x * 4 + (threadIdx.x >> 6);
    int s = w >> 9;          // / NT(512) points per slice
    int p = w & (NT - 1);
    int l = s % L;
    int gc = s / L;
    int c = gc % C;
    int g = gc / C;
    float d = (float)p * (CUTOFF / (float)(NT - 1));

    size_t wb = (size_t)((l * 3 + g) * C + c);
    const float* w1 = mlp_w1 + wb * NG * F;
    const float* w2 = mlp_w2 + wb * F * F;
    float w1c[NG], w2c[F];
    #pragma unroll
    for (int k = 0; k < NG; k++) w1c[k] = w1[k * F + lane];
    #pragma unroll
    for (int k = 0; k < F; k++) w2c[k] = w2[k * F + lane];
    float b1c = mlp_b1[wb * F + lane];
    float b2c = mlp_b2[wb * F + lane];

    float dd = d - (float)lane * SMEAR_STEP;
    float av = (lane < NG) ? __expf(SMEAR_COEFF * dd * dd) : 0.0f;
    float acc = b1c;
    #pragma unroll
    for (int k = 0; k < NG; k++) acc = fmaf(__shfl(av, k), w1c[k], acc);
    float t = sspf_fast(acc);
    float acc2 = b2c;
    #pragma unroll
    for (int j = 0; j < F; j++) acc2 = fmaf(__shfl(t, j), w2c[j], acc2);
    float ccut = 0.5f * (__cosf(d * PI_OVER_CUT) + 1.0f);
    tab[((size_t)s * NT + p) * 64 + lane] = acc2 * ccut;
}

// ---------------- LDS-tiled GEMM machinery (no shuffles) ----------------
// 256 threads; tile M=32 rows x N=64 cols, K=64 fully staged.
// thread (cg = t&15, rg = t>>4) computes rows {rg*2, rg*2+1} x cols [cg*4, cg*4+4).
// LDS rows padded to 68 floats: A-row reads hit banks {0,8,16,24} (conflict-free),
// B reads are 2-way aliased (free per m136).

__device__ inline void fma4(float acc[4], float a, const float4 b) {
    acc[0] = fmaf(a, b.x, acc[0]);
    acc[1] = fmaf(a, b.y, acc[1]);
    acc[2] = fmaf(a, b.z, acc[2]);
    acc[3] = fmaf(a, b.w, acc[3]);
}

__device__ inline void stage_A(const float* __restrict__ gA, float (*As)[68], int t) {
    #pragma unroll
    for (int i = 0; i < 2; i++) {
        int v = t + i * 256;            // 512 float4s = 32 rows x 16
        int r = v >> 4, c4 = (v & 15) * 4;
        *(float4*)&As[r][c4] = *(const float4*)(gA + (size_t)r * 64 + c4);
    }
}
__device__ inline void stage_B(const float* __restrict__ gB, float (*Bs)[68], int t) {
    #pragma unroll
    for (int i = 0; i < 4; i++) {
        int v = t + i * 256;            // 1024 float4s = 64 rows x 16
        int r = v >> 4, c4 = (v & 15) * 4;
        *(float4*)&Bs[r][c4] = *(const float4*)(gB + (size_t)r * 64 + c4);
    }
}
__device__ inline void gemm_tile(const float (*As)[68], const float (*Bs)[68],
                                 int r0, int c0, float acc0[4], float acc1[4]) {
    #pragma unroll 4
    for (int k0 = 0; k0 < 64; k0 += 4) {
        float4 a0 = *(const float4*)&As[r0][k0];
        float4 a1 = *(const float4*)&As[r0 + 1][k0];
        float4 b0 = *(const float4*)&Bs[k0][c0];
        float4 b1 = *(const float4*)&Bs[k0 + 1][c0];
        float4 b2 = *(const float4*)&Bs[k0 + 2][c0];
        float4 b3 = *(const float4*)&Bs[k0 + 3][c0];
        fma4(acc0, a0.x, b0); fma4(acc0, a0.y, b1);
        fma4(acc0, a0.z, b2); fma4(acc0, a0.w, b3);
        fma4(acc1, a1.x, b0); fma4(acc1, a1.y, b1);
        fma4(acc1, a1.z, b2); fma4(acc1, a1.w, b3);
    }
}

// xg[g] = h @ conv_w1[l,g]   (no bias, no act); grid 3*MT
__global__ __launch_bounds__(256) void k_lin1t(
    const float* __restrict__ h, const float* __restrict__ conv_w1,
    float* __restrict__ xg, int l) {
    __shared__ float As[TILE_M][68];
    __shared__ float Bs[64][68];
    int t = threadIdx.x;
    int g = blockIdx.x / MT;
    int tile = blockIdx.x - g * MT;
    stage_A(h + (size_t)tile * TILE_M * 64, As, t);
    stage_B(conv_w1 + (size_t)(l * 3 + g) * 64 * 64, Bs, t);
    __syncthreads();
    int cg = t & 15, rg = t >> 4;
    int c0 = cg * 4, r0 = rg * 2;
    float acc0[4] = {0, 0, 0, 0}, acc1[4] = {0, 0, 0, 0};
    gemm_tile(As, Bs, r0, c0, acc0, acc1);
    float* out = xg + ((size_t)g * NN + (size_t)tile * TILE_M) * 64;
    *(float4*)(out + (size_t)r0 * 64 + c0)       = make_float4(acc0[0], acc0[1], acc0[2], acc0[3]);
    *(float4*)(out + (size_t)(r0 + 1) * 64 + c0) = make_float4(acc1[0], acc1[1], acc1[2], acc1[3]);
}

// tmp[g] = ssp(agg3[g] @ conv_w2[l,g] + cb2[l,g]); tmp aliases xg; grid 3*MT
__global__ __launch_bounds__(256) void k_n2a(
    const float* __restrict__ agg3, const float* __restrict__ conv_w2,
    const float* __restrict__ conv_b2, float* __restrict__ tmp, int l) {
    __shared__ float As[TILE_M][68];
    __shared__ float Bs[64][68];
    int t = threadIdx.x;
    int g = blockIdx.x / MT;
    int tile = blockIdx.x - g * MT;
    size_t pb = (size_t)(l * 3 + g);
    stage_A(agg3 + ((size_t)g * NN + (size_t)tile * TILE_M) * 64, As, t);
    stage_B(conv_w2 + pb * 64 * 64, Bs, t);
    __syncthreads();
    int cg = t & 15, rg = t >> 4;
    int c0 = cg * 4, r0 = rg * 2;
    float4 bias = *(const float4*)(conv_b2 + pb * 64 + c0);
    float acc0[4] = {bias.x, bias.y, bias.z, bias.w};
    float acc1[4] = {bias.x, bias.y, bias.z, bias.w};
    gemm_tile(As, Bs, r0, c0, acc0, acc1);
    float* out = tmp + ((size_t)g * NN + (size_t)tile * TILE_M) * 64;
    *(float4*)(out + (size_t)r0 * 64 + c0) =
        make_float4(sspf(acc0[0]), sspf(acc0[1]), sspf(acc0[2]), sspf(acc0[3]));
    *(float4*)(out + (size_t)(r0 + 1) * 64 + c0) =
        make_float4(sspf(acc1[0]), sspf(acc1[1]), sspf(acc1[2]), sspf(acc1[3]));
}

// h += sum_g (tmp[g] @ blk_w[l,g] + blk_b[l,g]); grid MT, g-loop in-block
__global__ __launch_bounds__(256) void k_n2b(
    const float* __restrict__ tmp, const float* __restrict__ blk_w,
    const float* __restrict__ blk_b, float* __restrict__ h, int l) {
    __shared__ float As[TILE_M][68];
    __shared__ float Bs[64][68];
    int t = threadIdx.x;
    int tile = blockIdx.x;
    int cg = t & 15, rg = t >> 4;
    int c0 = cg * 4, r0 = rg * 2;
    float osum0[4] = {0, 0, 0, 0}, osum1[4] = {0, 0, 0, 0};
    for (int g = 0; g < 3; g++) {
        if (g) __syncthreads();   // previous iteration's reads done before restage
        size_t pb = (size_t)(l * 3 + g);
        stage_A(tmp + ((size_t)g * NN + (size_t)tile * TILE_M) * 64, As, t);
        stage_B(blk_w + pb * 64 * 64, Bs, t);
        __syncthreads();
        float4 bias = *(const float4*)(blk_b + pb * 64 + c0);
        float acc0[4] = {bias.x, bias.y, bias.z, bias.w};
        float acc1[4] = {bias.x, bias.y, bias.z, bias.w};
        gemm_tile(As, Bs, r0, c0, acc0, acc1);
        #pragma unroll
        for (int j = 0; j < 4; j++) { osum0[j] += acc0[j]; osum1[j] += acc1[j]; }
    }
    float* hp = h + ((size_t)tile * TILE_M) * 64;
    float4 h0 = *(float4*)(hp + (size_t)r0 * 64 + c0);
    float4 h1 = *(float4*)(hp + (size_t)(r0 + 1) * 64 + c0);
    *(float4*)(hp + (size_t)r0 * 64 + c0) =
        make_float4(h0.x + osum0[0], h0.y + osum0[1], h0.z + osum0[2], h0.w + osum0[3]);
    *(float4*)(hp + (size_t)(r0 + 1) * 64 + c0) =
        make_float4(h1.x + osum1[0], h1.y + osum1[1], h1.z + osum1[2], h1.w + osum1[3]);
}

// ---------------- aggregation (unchanged) ----------------
__global__ __launch_bounds__(256) void k_agg(
    const int4* __restrict__ edata, const int* __restrict__ base,
    const float* __restrict__ xg, const float* __restrict__ tab,
    float* __restrict__ agg3, int l) {
    const int lane = threadIdx.x & 63;
    int w = blockIdx.x * 4 + (threadIdx.x >> 6); // 0..7199
    int g = w / AT;
    int dst = w - g * AT;
    const int4* ed = edata + graph_off(g);
    int s = base[g * (AT + 1) + dst];
    int e = base[g * (AT + 1) + dst + 1];
    const float* tg = tab + ((size_t)g * C * L * NT) * 64 + (size_t)l * NT * 64;
    const float* xgg = xg + (size_t)g * NN * F;
    float acc[BS];
    #pragma unroll
    for (int b = 0; b < BS; b++) acc[b] = 0.0f;
    int i = s;
    for (; i + 2 <= e; i += 2) {
        int4 mA = ed[i], mB = ed[i + 1];
        const float* rA = tg + (size_t)mA.y * 64;
        const float* rB = tg + (size_t)mB.y * 64;
        float frA = __int_as_float(mA.z), frB = __int_as_float(mB.z);
        float rA0 = rA[lane], rA1 = rA[64 + lane];
        float rB0 = rB[lane], rB1 = rB[64 + lane];
        float wvA = fmaf(frA, rA1 - rA0, rA0);
        float wvB = fmaf(frB, rB1 - rB0, rB0);
        const float* xbA = xgg + (size_t)mA.x * F + lane;
        const float* xbB = xgg + (size_t)mB.x * F + lane;
        #pragma unroll
        for (int b = 0; b < BS; b++) {
            acc[b] = fmaf(xbA[(size_t)b * AT * F], wvA, acc[b]);
            acc[b] = fmaf(xbB[(size_t)b * AT * F], wvB, acc[b]);
        }
    }
    if (i < e) {
        int4 m = ed[i];
        const float* r = tg + (size_t)m.y * 64;
        float fr = __int_as_float(m.z);
        float r0 = r[lane], r1 = r[64 + lane];
        float wv = fmaf(fr, r1 - r0, r0);
        const float* xb = xgg + (size_t)m.x * F + lane;
        #pragma unroll
        for (int b = 0; b < BS; b++)
            acc[b] = fmaf(xb[(size_t)b * AT * F], wv, acc[b]);
    }
    float* ao = agg3 + ((size_t)g * NN + dst) * F + lane;
    #pragma unroll
    for (int b = 0; b < BS; b++) ao[(size_t)b * AT * F] = acc[b];
}

// Readout: o[b] = sum_pore h . weff + M2*(b1.W2 + b2), weff = W1@W2
__global__ void k_read(const float* __restrict__ h,
                       const float* __restrict__ w1, const float* __restrict__ b1,
                       const float* __restrict__ w2, const float* __restrict__ b2,
                       float* __restrict__ out) {
    int b = blockIdx.x;
    int lane = threadIdx.x & 63;
    int wv = threadIdx.x >> 6;
    __shared__ float part[4];
    float weff = 0.0f;
    #pragma unroll
    for (int j = 0; j < H / 2; j++) weff = fmaf(w1[lane * (H / 2) + j], w2[j], weff);
    float acc = 0.0f;
    for (int i = wv * (M2 / 4); i < (wv + 1) * (M2 / 4); i++)
        acc += h[((size_t)b * AT + M1 + i) * H + lane];
    float v = acc * weff;
    for (int off = 32; off; off >>= 1) v += __shfl_xor(v, off);
    if (lane == 0) part[wv] = v;
    __syncthreads();
    if (threadIdx.x == 0) {
        float bias = b2[0];
        for (int j = 0; j < H / 2; j++) bias = fmaf(b1[j], w2[j], bias);
        out[b] = part[0] + part[1] + part[2] + part[3] + (float)M2 * bias;
    }
}

// ---------------- launcher ----------------
extern "C" void kernel_launch(void* const* d_in, const int* in_sizes, int n_in,
                              void* d_out, int out_size, void* d_ws, size_t ws_size,
                              hipStream_t stream) {
    const int* sites   = (const int*)d_in[0];
    const int* sites_p = (const int*)d_in[1];
    const int* ei1 = (const int*)d_in[2];
    const float* ew1 = (const float*)d_in[3];
    const int* c1 = (const int*)d_in[4];
    const int* ei2 = (const int*)d_in[5];
    const float* ew2 = (const float*)d_in[6];
    const int* c2 = (const int*)d_in[7];
    const int* ei3 = (const int*)d_in[8];
    const float* ew3 = (const float*)d_in[9];
    const int* c3 = (const int*)d_in[10];
    const float* emb_w   = (const float*)d_in[11];
    const float* emb_p_w = (const float*)d_in[12];
    const float* mlp_w1 = (const float*)d_in[13];
    const float* mlp_b1 = (const float*)d_in[14];
    const float* mlp_w2 = (const float*)d_in[15];
    const float* mlp_b2 = (const float*)d_in[16];
    const float* conv_w1 = (const float*)d_in[17];
    const float* conv_w2 = (const float*)d_in[18];
    const float* conv_b2 = (const float*)d_in[19];
    const float* blk_w = (const float*)d_in[20];
    const float* blk_b = (const float*)d_in[21];
    const float* out_w1 = (const float*)d_in[22];
    const float* out_b1 = (const float*)d_in[23];
    const float* out_w2 = (const float*)d_in[24];
    const float* out_b2 = (const float*)d_in[25];

    char* ws = (char*)d_ws;
    float* h    = (float*)(ws + O_H);
    float* xg   = (float*)(ws + O_XG);   // also tmp for n2a/n2b
    float* agg3 = (float*)(ws + O_AGG);
    float* tab  = (float*)(ws + O_TAB);
    int4*  edata = (int4*)(ws + O_EDATA);
    int* ip    = (int*)(ws + O_INT);
    int* deg   = ip + I_DEG;
    int* cur   = ip + I_CUR;
    int* ibase = ip + I_BASE;

    hipMemsetAsync(ip, 0, (size_t)I_ZEND * sizeof(int), stream);

    // one WAVE per (slice,point): 48*NT waves = 48*NT/4 blocks of 256 threads
    k_table<<<48 * NT / 4, 256, 0, stream>>>(mlp_w1, mlp_b1, mlp_w2, mlp_b2, tab);
    k_init_h<<<(NN * 64 + 255) / 256, 256, 0, stream>>>(sites, sites_p, emb_w, emb_p_w, h);
    k_count<<<NBLK, 256, 0, stream>>>(ei1, ei2, ei3, c1, c2, c3, deg);
    k_scan<<<3, 256, 0, stream>>>(deg, ibase);
    k_fill<<<NBLK, 256, 0, stream>>>(ei1, ei2, ei3, c1, c2, c3, ew1, ew2, ew3,
                                     ibase, cur, edata);

    for (int l = 0; l < L; l++) {
        k_lin1t<<<3 * MT, 256, 0, stream>>>(h, conv_w1, xg, l);
        k_agg<<<3 * AT / 4, 256, 0, stream>>>(edata, ibase, xg, tab, agg3, l);
        k_n2a<<<3 * MT, 256, 0, stream>>>(agg3, conv_w2, conv_b2, xg, l);
        k_n2b<<<MT, 256, 0, stream>>>(xg, blk_w, blk_b, h, l);
    }
    k_read<<<BS, 256, 0, stream>>>(h, out_w1, out_b1, out_w2, out_b2, (float*)d_out);
}

// Round 8
// 461.391 us; speedup vs baseline: 6.9601x; 1.1084x over previous
//
#include <hip/hip_runtime.h>
#include <math.h>

// ---------------- problem constants ----------------
constexpr int M1 = 2000, M2 = 400, BS = 8;
constexpr int AT = M1 + M2;            // 2400
constexpr int NN = BS * AT;            // 19200 nodes
constexpr int E1 = 60000, E2 = 20000, E3 = 20000;
constexpr int ET = E1 + E2 + E3;       // 100000
constexpr int H = 64, F = 64, NG = 50, L = 4, C = 4;
constexpr float CUTOFF = 10.0f;
constexpr float LOG2F_ = 0.6931471805599453f;

constexpr float SMEAR_STEP = 10.0f / 49.0f;
constexpr float SMEAR_COEFF = -12.005f;
constexpr float PI_OVER_CUT = 0.31415926535897932f; // pi/10

constexpr int NBLK = (ET + 255) / 256;  // 391 blocks in count/fill passes

// Edge-MLP lerp table: NT points over [0,CUTOFF] per (g,c,l) slice (48 slices).
constexpr int NT = 512;
constexpr float DSCALE = (float)(NT - 1) / CUTOFF;   // 51.1

// GEMM tiling
constexpr int TILE_M = 32;
constexpr int MT = NN / TILE_M;        // 600 row-tiles (75 per structure: aligned)

// ---------------- workspace layout (bytes) ----------------
constexpr size_t O_H     = 0;                           // h   [NN,64] f32 (4.9MB)
constexpr size_t O_XG    = O_H   + (size_t)NN * 64 * 4; // xg  [3][AT][BS][64] b-major
constexpr size_t O_AGG   = O_XG  + (size_t)3 * NN * 64 * 4; // agg3 [3,NN,64] n-major
constexpr size_t O_TAB   = O_AGG + (size_t)3 * NN * 64 * 4; // tab [48,NT,64] (6.3MB)
constexpr size_t O_EDATA = O_TAB + (size_t)48 * NT * 64 * 4; // edata [ET] int4 (1.6MB)
constexpr size_t O_INT   = O_EDATA + (size_t)ET * 16;
// int region (element offsets from O_INT):
constexpr int I_DEG  = 0;      // [3*AT] zeroed
constexpr int I_CUR  = 7200;   // [3*AT] zeroed
constexpr int I_ZEND = 14400;
constexpr int I_BASE = 14400;  // [3*(AT+1)] = 7203, reserve 7216

__device__ inline float sspf(float x) {
    return fmaxf(x, 0.0f) + log1pf(expf(-fabsf(x))) - LOG2F_;
}
__device__ inline float sspf_fast(float x) {
    float t = __expf(-fabsf(x));
    return fmaxf(x, 0.0f) + __logf(1.0f + t) - LOG2F_;
}

__device__ inline int graph_off(int g) { return g == 0 ? 0 : (g == 1 ? E1 : E1 + E2); }

__device__ inline void edge_decode(int idx, int& g, int& e,
                                   const int* ei1, const int* ei2, const int* ei3,
                                   const int* c1, const int* c2, const int* c3,
                                   const int*& ei, const int*& cl) {
    if (idx < E1)            { g = 0; e = idx;           ei = ei1; cl = c1; }
    else if (idx < E1 + E2)  { g = 1; e = idx - E1;      ei = ei2; cl = c2; }
    else                     { g = 2; e = idx - E1 - E2; ei = ei3; cl = c3; }
}

// ---------------- setup kernels ----------------
__global__ void k_init_h(const int* __restrict__ sites, const int* __restrict__ sites_p,
                         const float* __restrict__ emb_w, const float* __restrict__ emb_p_w,
                         float* __restrict__ h) {
    int idx = blockIdx.x * blockDim.x + threadIdx.x;
    if (idx >= NN * 64) return;
    int f = idx & 63;
    int n = idx >> 6;
    int b = n / AT;
    int i = n - b * AT;
    float v;
    if (i < M1) v = emb_w[sites[b * M1 + i] * H + f];
    else        v = emb_p_w[sites_p[b * M2 + (i - M1)] * H + f];
    h[idx] = v;
}

__global__ void k_count(const int* __restrict__ ei1, const int* __restrict__ ei2,
                        const int* __restrict__ ei3, const int* __restrict__ c1,
                        const int* __restrict__ c2, const int* __restrict__ c3,
                        int* __restrict__ deg) {
    int idx = blockIdx.x * blockDim.x + threadIdx.x;
    if (idx >= ET) return;
    int g, e; const int* ei; const int* cl;
    edge_decode(idx, g, e, ei1, ei2, ei3, c1, c2, c3, ei, cl);
    atomicAdd(&deg[g * AT + ei[2 * e + 1]], 1);
}

__global__ void k_scan(const int* __restrict__ deg, int* __restrict__ base) {
    const int T = 256, CH = 10; // 2560 >= 2400
    int t = threadIdx.x;
    __shared__ int lsum[T];
    int g = blockIdx.x;
    int loc[CH];
    int s = 0;
    #pragma unroll
    for (int i = 0; i < CH; i++) {
        int idx = t * CH + i;
        int v = (idx < AT) ? deg[g * AT + idx] : 0;
        loc[i] = s;
        s += v;
    }
    lsum[t] = s;
    __syncthreads();
    for (int off = 1; off < T; off <<= 1) {
        int v = 0;
        if (t >= off) v = lsum[t - off];
        __syncthreads();
        lsum[t] += v;
        __syncthreads();
    }
    int tb = lsum[t] - s;
    #pragma unroll
    for (int i = 0; i < CH; i++) {
        int idx = t * CH + i;
        if (idx < AT) base[g * (AT + 1) + idx] = tb + loc[i];
    }
    if (t == T - 1) base[g * (AT + 1) + AT] = lsum[T - 1];
}

__global__ void k_fill(const int* __restrict__ ei1, const int* __restrict__ ei2,
                       const int* __restrict__ ei3, const int* __restrict__ c1,
                       const int* __restrict__ c2, const int* __restrict__ c3,
                       const float* __restrict__ ew1, const float* __restrict__ ew2,
                       const float* __restrict__ ew3,
                       const int* __restrict__ base, int* __restrict__ cur,
                       int4* __restrict__ edata) {
    int idx = blockIdx.x * blockDim.x + threadIdx.x;
    if (idx >= ET) return;
    int g, e; const int* ei; const int* cl;
    edge_decode(idx, g, e, ei1, ei2, ei3, c1, c2, c3, ei, cl);
    const float* ew = (g == 0) ? ew1 : (g == 1 ? ew2 : ew3);
    int dst = ei[2 * e + 1];
    int src = ei[2 * e];
    int p = base[g * (AT + 1) + dst] + atomicAdd(&cur[g * AT + dst], 1);
    float t = ew[e] * DSCALE;
    int i0 = min((int)t, NT - 2);
    float fr = t - (float)i0;
    int cb = cl[e] * (L * NT) + i0;
    edata[graph_off(g) + p] = make_int4(src, cb, __float_as_int(fr), 0);
}

// ---------------- edge-MLP table build ----------------
__global__ __launch_bounds__(256) void k_table(
    const float* __restrict__ mlp_w1, const float* __restrict__ mlp_b1,
    const float* __restrict__ mlp_w2, const float* __restrict__ mlp_b2,
    float* __restrict__ tab) {
    const int lane = threadIdx.x & 63;
    int w = blockIdx.x * 4 + (threadIdx.x >> 6);
    int s = w >> 9;          // / NT(512) points per slice
    int p = w & (NT - 1);
    int l = s % L;
    int gc = s / L;
    int c = gc % C;
    int g = gc / C;
    float d = (float)p * (CUTOFF / (float)(NT - 1));

    size_t wb = (size_t)((l * 3 + g) * C + c);
    const float* w1 = mlp_w1 + wb * NG * F;
    const float* w2 = mlp_w2 + wb * F * F;
    float w1c[NG], w2c[F];
    #pragma unroll
    for (int k = 0; k < NG; k++) w1c[k] = w1[k * F + lane];
    #pragma unroll
    for (int k = 0; k < F; k++) w2c[k] = w2[k * F + lane];
    float b1c = mlp_b1[wb * F + lane];
    float b2c = mlp_b2[wb * F + lane];

    float dd = d - (float)lane * SMEAR_STEP;
    float av = (lane < NG) ? __expf(SMEAR_COEFF * dd * dd) : 0.0f;
    float acc = b1c;
    #pragma unroll
    for (int k = 0; k < NG; k++) acc = fmaf(__shfl(av, k), w1c[k], acc);
    float t = sspf_fast(acc);
    float acc2 = b2c;
    #pragma unroll
    for (int j = 0; j < F; j++) acc2 = fmaf(__shfl(t, j), w2c[j], acc2);
    float ccut = 0.5f * (__cosf(d * PI_OVER_CUT) + 1.0f);
    tab[((size_t)s * NT + p) * 64 + lane] = acc2 * ccut;
}

// ---------------- LDS-tiled GEMM machinery ----------------
// 256 threads; tile M=32 x N=64, K=64 staged. thread (cg=t&15, rg=t>>4)
// computes rows {rg*2, rg*2+1} x cols [cg*4, cg*4+4). Rows padded to 68.

__device__ inline void fma4(float acc[4], float a, const float4 b) {
    acc[0] = fmaf(a, b.x, acc[0]);
    acc[1] = fmaf(a, b.y, acc[1]);
    acc[2] = fmaf(a, b.z, acc[2]);
    acc[3] = fmaf(a, b.w, acc[3]);
}

__device__ inline void stage_A(const float* __restrict__ gA, float (*As)[68], int t) {
    #pragma unroll
    for (int i = 0; i < 2; i++) {
        int v = t + i * 256;            // 512 float4s = 32 rows x 16
        int r = v >> 4, c4 = (v & 15) * 4;
        *(float4*)&As[r][c4] = *(const float4*)(gA + (size_t)r * 64 + c4);
    }
}
__device__ inline void stage_B(const float* __restrict__ gB, float (*Bs)[68], int t) {
    #pragma unroll
    for (int i = 0; i < 4; i++) {
        int v = t + i * 256;            // 1024 float4s = 64 rows x 16
        int r = v >> 4, c4 = (v & 15) * 4;
        *(float4*)&Bs[r][c4] = *(const float4*)(gB + (size_t)r * 64 + c4);
    }
}
__device__ inline void gemm_tile(const float (*As)[68], const float (*Bs)[68],
                                 int r0, int c0, float acc0[4], float acc1[4]) {
    #pragma unroll 4
    for (int k0 = 0; k0 < 64; k0 += 4) {
        float4 a0 = *(const float4*)&As[r0][k0];
        float4 a1 = *(const float4*)&As[r0 + 1][k0];
        float4 b0 = *(const float4*)&Bs[k0][c0];
        float4 b1 = *(const float4*)&Bs[k0 + 1][c0];
        float4 b2 = *(const float4*)&Bs[k0 + 2][c0];
        float4 b3 = *(const float4*)&Bs[k0 + 3][c0];
        fma4(acc0, a0.x, b0); fma4(acc0, a0.y, b1);
        fma4(acc0, a0.z, b2); fma4(acc0, a0.w, b3);
        fma4(acc1, a1.x, b0); fma4(acc1, a1.y, b1);
        fma4(acc1, a1.z, b2); fma4(acc1, a1.w, b3);
    }
}

// xg store in b-major layout: xg[((g*AT + i)*BS + b)*64 + c]
__device__ inline void store_xg(float* __restrict__ xg, int g, int n, int c0,
                                const float acc[4]) {
    int b = n / AT;
    int i = n - b * AT;
    float* out = xg + (((size_t)g * AT + i) * BS + b) * 64 + c0;
    *(float4*)out = make_float4(acc[0], acc[1], acc[2], acc[3]);
}

// xg[g] = h @ conv_w1[l,g]   (initial lin1, l=0); grid 3*MT
__global__ __launch_bounds__(256) void k_lin1t(
    const float* __restrict__ h, const float* __restrict__ conv_w1,
    float* __restrict__ xg, int l) {
    __shared__ float As[TILE_M][68];
    __shared__ float Bs[64][68];
    int t = threadIdx.x;
    int g = blockIdx.x / MT;
    int tile = blockIdx.x - g * MT;
    stage_A(h + (size_t)tile * TILE_M * 64, As, t);
    stage_B(conv_w1 + (size_t)(l * 3 + g) * 64 * 64, Bs, t);
    __syncthreads();
    int cg = t & 15, rg = t >> 4;
    int c0 = cg * 4, r0 = rg * 2;
    float acc0[4] = {0, 0, 0, 0}, acc1[4] = {0, 0, 0, 0};
    gemm_tile(As, Bs, r0, c0, acc0, acc1);
    int n0 = tile * TILE_M;
    store_xg(xg, g, n0 + r0, c0, acc0);
    store_xg(xg, g, n0 + r0 + 1, c0, acc1);
}

// Fused: tmp_g = ssp(agg_g@cw2+cb2) [LDS]; h += sum_g tmp_g@bw_g+bb_g;
// then xg = h'@cw1[l+1] for next layer. grid MT.
__global__ __launch_bounds__(256) void k_layer(
    const float* __restrict__ agg3, const float* __restrict__ conv_w2,
    const float* __restrict__ conv_b2, const float* __restrict__ blk_w,
    const float* __restrict__ blk_b, const float* __restrict__ conv_w1,
    float* __restrict__ h, float* __restrict__ xg, int l, int last) {
    __shared__ float As[TILE_M][68];
    __shared__ float Bs[64][68];
    __shared__ float Ts[TILE_M][68];
    int t = threadIdx.x;
    int tile = blockIdx.x;
    int cg = t & 15, rg = t >> 4;
    int c0 = cg * 4, r0 = rg * 2;
    float osum0[4] = {0, 0, 0, 0}, osum1[4] = {0, 0, 0, 0};
    #pragma unroll 1
    for (int g = 0; g < 3; g++) {
        size_t pb = (size_t)(l * 3 + g);
        if (g) __syncthreads();          // prior gemm2 reads of Bs done
        stage_A(agg3 + ((size_t)g * NN + (size_t)tile * TILE_M) * 64, As, t);
        stage_B(conv_w2 + pb * 4096, Bs, t);
        __syncthreads();
        float4 bias = *(const float4*)(conv_b2 + pb * 64 + c0);
        float a0[4] = {bias.x, bias.y, bias.z, bias.w};
        float a1[4] = {bias.x, bias.y, bias.z, bias.w};
        gemm_tile(As, Bs, r0, c0, a0, a1);
        *(float4*)&Ts[r0][c0] =
            make_float4(sspf(a0[0]), sspf(a0[1]), sspf(a0[2]), sspf(a0[3]));
        *(float4*)&Ts[r0 + 1][c0] =
            make_float4(sspf(a1[0]), sspf(a1[1]), sspf(a1[2]), sspf(a1[3]));
        __syncthreads();                 // gemm1 reads done, Ts fully written
        stage_B(blk_w + pb * 4096, Bs, t);
        __syncthreads();
        float4 bb = *(const float4*)(blk_b + pb * 64 + c0);
        float b0[4] = {bb.x, bb.y, bb.z, bb.w};
        float b1[4] = {bb.x, bb.y, bb.z, bb.w};
        gemm_tile(Ts, Bs, r0, c0, b0, b1);
        #pragma unroll
        for (int j = 0; j < 4; j++) { osum0[j] += b0[j]; osum1[j] += b1[j]; }
    }
    // h += osum; keep h' tile in As for the next-layer lin1 GEMM
    float* hp = h + (size_t)tile * TILE_M * 64;
    float4 h0 = *(float4*)(hp + (size_t)r0 * 64 + c0);
    float4 h1 = *(float4*)(hp + (size_t)(r0 + 1) * 64 + c0);
    h0.x += osum0[0]; h0.y += osum0[1]; h0.z += osum0[2]; h0.w += osum0[3];
    h1.x += osum1[0]; h1.y += osum1[1]; h1.z += osum1[2]; h1.w += osum1[3];
    *(float4*)(hp + (size_t)r0 * 64 + c0) = h0;
    *(float4*)(hp + (size_t)(r0 + 1) * 64 + c0) = h1;
    if (last) return;
    *(float4*)&As[r0][c0] = h0;          // safe: As last read before g=2's mid-sync
    *(float4*)&As[r0 + 1][c0] = h1;
    int n0 = tile * TILE_M;
    #pragma unroll 1
    for (int g = 0; g < 3; g++) {
        __syncthreads();                 // As writes visible; prior Bs reads done
        stage_B(conv_w1 + (size_t)((l + 1) * 3 + g) * 4096, Bs, t);
        __syncthreads();
        float x0[4] = {0, 0, 0, 0}, x1[4] = {0, 0, 0, 0};
        gemm_tile(As, Bs, r0, c0, x0, x1);
        store_xg(xg, g, n0 + r0, c0, x0);
        store_xg(xg, g, n0 + r0 + 1, c0, x1);
    }
}

// ---------------- aggregation ----------------
// One wave per (g,dst); per edge: one int4 record + table lerp; 8 batches in
// registers; b-major xg layout makes the 8-batch gather one 2KB contiguous run.
__global__ __launch_bounds__(256) void k_agg(
    const int4* __restrict__ edata, const int* __restrict__ base,
    const float* __restrict__ xg, const float* __restrict__ tab,
    float* __restrict__ agg3, int l) {
    const int lane = threadIdx.x & 63;
    int w = blockIdx.x * 4 + (threadIdx.x >> 6); // 0..7199
    int g = w / AT;
    int dst = w - g * AT;
    const int4* ed = edata + graph_off(g);
    int s = base[g * (AT + 1) + dst];
    int e = base[g * (AT + 1) + dst + 1];
    const float* tg = tab + ((size_t)g * C * L * NT) * 64 + (size_t)l * NT * 64;
    const float* xgg = xg + (size_t)g * AT * BS * 64;
    float acc[BS];
    #pragma unroll
    for (int b = 0; b < BS; b++) acc[b] = 0.0f;
    int i = s;
    for (; i + 2 <= e; i += 2) {
        int4 mA = ed[i], mB = ed[i + 1];
        const float* rA = tg + (size_t)mA.y * 64;
        const float* rB = tg + (size_t)mB.y * 64;
        float frA = __int_as_float(mA.z), frB = __int_as_float(mB.z);
        float rA0 = rA[lane], rA1 = rA[64 + lane];
        float rB0 = rB[lane], rB1 = rB[64 + lane];
        float wvA = fmaf(frA, rA1 - rA0, rA0);
        float wvB = fmaf(frB, rB1 - rB0, rB0);
        const float* xbA = xgg + (size_t)mA.x * (BS * 64) + lane;
        const float* xbB = xgg + (size_t)mB.x * (BS * 64) + lane;
        #pragma unroll
        for (int b = 0; b < BS; b++) {
            acc[b] = fmaf(xbA[b * 64], wvA, acc[b]);
            acc[b] = fmaf(xbB[b * 64], wvB, acc[b]);
        }
    }
    if (i < e) {
        int4 m = ed[i];
        const float* r = tg + (size_t)m.y * 64;
        float fr = __int_as_float(m.z);
        float r0 = r[lane], r1 = r[64 + lane];
        float wv = fmaf(fr, r1 - r0, r0);
        const float* xb = xgg + (size_t)m.x * (BS * 64) + lane;
        #pragma unroll
        for (int b = 0; b < BS; b++)
            acc[b] = fmaf(xb[b * 64], wv, acc[b]);
    }
    float* ao = agg3 + ((size_t)g * NN + dst) * F + lane;
    #pragma unroll
    for (int b = 0; b < BS; b++) ao[(size_t)b * AT * F] = acc[b];
}

// Readout: o[b] = sum_pore h . weff + M2*(b1.W2 + b2), weff = W1@W2
__global__ void k_read(const float* __restrict__ h,
                       const float* __restrict__ w1, const float* __restrict__ b1,
                       const float* __restrict__ w2, const float* __restrict__ b2,
                       float* __restrict__ out) {
    int b = blockIdx.x;
    int lane = threadIdx.x & 63;
    int wv = threadIdx.x >> 6;
    __shared__ float part[4];
    float weff = 0.0f;
    #pragma unroll
    for (int j = 0; j < H / 2; j++) weff = fmaf(w1[lane * (H / 2) + j], w2[j], weff);
    float acc = 0.0f;
    for (int i = wv * (M2 / 4); i < (wv + 1) * (M2 / 4); i++)
        acc += h[((size_t)b * AT + M1 + i) * H + lane];
    float v = acc * weff;
    for (int off = 32; off; off >>= 1) v += __shfl_xor(v, off);
    if (lane == 0) part[wv] = v;
    __syncthreads();
    if (threadIdx.x == 0) {
        float bias = b2[0];
        for (int j = 0; j < H / 2; j++) bias = fmaf(b1[j], w2[j], bias);
        out[b] = part[0] + part[1] + part[2] + part[3] + (float)M2 * bias;
    }
}

// ---------------- launcher ----------------
extern "C" void kernel_launch(void* const* d_in, const int* in_sizes, int n_in,
                              void* d_out, int out_size, void* d_ws, size_t ws_size,
                              hipStream_t stream) {
    const int* sites   = (const int*)d_in[0];
    const int* sites_p = (const int*)d_in[1];
    const int* ei1 = (const int*)d_in[2];
    const float* ew1 = (const float*)d_in[3];
    const int* c1 = (const int*)d_in[4];
    const int* ei2 = (const int*)d_in[5];
    const float* ew2 = (const float*)d_in[6];
    const int* c2 = (const int*)d_in[7];
    const int* ei3 = (const int*)d_in[8];
    const float* ew3 = (const float*)d_in[9];
    const int* c3 = (const int*)d_in[10];
    const float* emb_w   = (const float*)d_in[11];
    const float* emb_p_w = (const float*)d_in[12];
    const float* mlp_w1 = (const float*)d_in[13];
    const float* mlp_b1 = (const float*)d_in[14];
    const float* mlp_w2 = (const float*)d_in[15];
    const float* mlp_b2 = (const float*)d_in[16];
    const float* conv_w1 = (const float*)d_in[17];
    const float* conv_w2 = (const float*)d_in[18];
    const float* conv_b2 = (const float*)d_in[19];
    const float* blk_w = (const float*)d_in[20];
    const float* blk_b = (const float*)d_in[21];
    const float* out_w1 = (const float*)d_in[22];
    const float* out_b1 = (const float*)d_in[23];
    const float* out_w2 = (const float*)d_in[24];
    const float* out_b2 = (const float*)d_in[25];

    char* ws = (char*)d_ws;
    float* h    = (float*)(ws + O_H);
    float* xg   = (float*)(ws + O_XG);
    float* agg3 = (float*)(ws + O_AGG);
    float* tab  = (float*)(ws + O_TAB);
    int4*  edata = (int4*)(ws + O_EDATA);
    int* ip    = (int*)(ws + O_INT);
    int* deg   = ip + I_DEG;
    int* cur   = ip + I_CUR;
    int* ibase = ip + I_BASE;

    hipMemsetAsync(ip, 0, (size_t)I_ZEND * sizeof(int), stream);

    k_table<<<48 * NT / 4, 256, 0, stream>>>(mlp_w1, mlp_b1, mlp_w2, mlp_b2, tab);
    k_init_h<<<(NN * 64 + 255) / 256, 256, 0, stream>>>(sites, sites_p, emb_w, emb_p_w, h);
    k_count<<<NBLK, 256, 0, stream>>>(ei1, ei2, ei3, c1, c2, c3, deg);
    k_scan<<<3, 256, 0, stream>>>(deg, ibase);
    k_fill<<<NBLK, 256, 0, stream>>>(ei1, ei2, ei3, c1, c2, c3, ew1, ew2, ew3,
                                     ibase, cur, edata);

    k_lin1t<<<3 * MT, 256, 0, stream>>>(h, conv_w1, xg, 0);
    for (int l = 0; l < L; l++) {
        k_agg<<<3 * AT / 4, 256, 0, stream>>>(edata, ibase, xg, tab, agg3, l);
        k_layer<<<MT, 256, 0, stream>>>(agg3, conv_w2, conv_b2, blk_w, blk_b,
                                        conv_w1, h, xg, l, (l == L - 1) ? 1 : 0);
    }
    k_read<<<BS, 256, 0, stream>>>(h, out_w1, out_b1, out_w2, out_b2, (float*)d_out);
}